// Round 8
// baseline (575.089 us; speedup 1.0000x reference)
//
#include <hip/hip_runtime.h>
#include <hip/hip_bf16.h>

#define B_   256
#define P_   100
#define H_   512
#define NH_  16
#define HD_  32
#define VN_  221
#define KNODE 201
#define KVEH  21
#define KVND  20
#define CSD_ 16
#define MASKP 224                       // padded mask row stride (aligned dwords)

typedef __attribute__((ext_vector_type(8))) short short8;
typedef __attribute__((ext_vector_type(4))) float f32x4;

__device__ __forceinline__ unsigned cvtpk(float lo, float hi) {
    unsigned r;
    asm("v_cvt_pk_bf16_f32 %0, %1, %2" : "=v"(r) : "v"(lo), "v"(hi));
    return r;
}
__device__ __forceinline__ unsigned f2bf(float f) {
    union { float f; unsigned u; } x; x.f = f;
    return (x.u + 0x7FFFu + ((x.u >> 16) & 1u)) >> 16;   // RNE bf16 bits
}

// ------------------------------------------------------------------
// mask dtype probe + repack to padded [B*P][224] u8 (pad = 1 = illegal)
// ------------------------------------------------------------------
__global__ void mask_detect_kernel(const unsigned int* __restrict__ w,
                                   int nwords, int* __restrict__ flag) {
    int i = blockIdx.x * 256 + threadIdx.x;
    if (i < nwords && (w[i] & ~1u)) atomicOr(flag, 1);
}

__global__ void mask_repack_kernel(const unsigned char* __restrict__ mb,
                                   const int* __restrict__ mw,
                                   const int* __restrict__ flag,
                                   unsigned char* __restrict__ out) {
    int i = blockIdx.x * blockDim.x + threadIdx.x;
    if (i >= B_ * P_ * MASKP) return;
    int row = i / MASKP, k = i - row * MASKP;
    unsigned char v = 1;
    if (k < VN_) {
        int src = row * VN_ + k;
        v = (*flag) ? (unsigned char)(mb[src] != 0) : (unsigned char)(mw[src] != 0);
    }
    out[i] = v;
}

// ------------------------------------------------------------------
// concat-key -> clamped source row pointer (folds to 1 branch for
// interior chunks; clamped rows are valid memory, scores masked off)
// ------------------------------------------------------------------
__device__ __forceinline__ const float* krow(
    const float* __restrict__ kgb, const float* __restrict__ knb,
    const float* __restrict__ kvb, const float* __restrict__ kvnb, int key)
{
    if (key < 224) { int r = key < 220 ? key : 220; return kgb + r * 32; }
    if (key < 432) { int r = key - 224; r = r < 200 ? r : 200; return knb + r * 32; }
    if (key < 456) { int r = key - 432; r = r < 20 ? r : 20; return kvb + r * 32; }
    int r = key - 456; r = r < 19 ? r : 19; return kvnb + r * 32;
}

// ------------------------------------------------------------------
// one source: K-frags direct from global f32 (+cvtpk), QK MFMA, exp2,
// bpermute-gather P, PV MFMA from V^T LDS. Low-register, per-chunk.
// ------------------------------------------------------------------
template<bool MASKED, int C0, int C1, int LO, int HI>
__device__ __forceinline__ void attend_v4(
    const char* __restrict__ vlds,
    const unsigned char* __restrict__ mrow,
    const float* __restrict__ kgb, const float* __restrict__ knb,
    const float* __restrict__ kvb, const float* __restrict__ kvnb,
    short8 qf, int g, int qr, int addrA, int addrB,
    f32x4& O0, f32x4& O1)
{
    f32x4 A0 = {0.f,0.f,0.f,0.f}, A1 = {0.f,0.f,0.f,0.f};
    float ssum = 0.f;
    const bool sel = g < 2;
    #pragma unroll
    for (int c = C0; c <= C1; ++c) {
        const int kb = c * 32;
        const float* p0 = krow(kgb, knb, kvb, kvnb, kb + qr);
        const float* p1 = krow(kgb, knb, kvb, kvnb, kb + 16 + qr);
        float4 a0 = *(const float4*)(p0 + 8 * g);
        float4 a1 = *(const float4*)(p0 + 8 * g + 4);
        float4 b0 = *(const float4*)(p1 + 8 * g);
        float4 b1 = *(const float4*)(p1 + 8 * g + 4);
        union { unsigned u[4]; short8 s8; } kf0, kf1;
        kf0.u[0] = cvtpk(a0.x, a0.y); kf0.u[1] = cvtpk(a0.z, a0.w);
        kf0.u[2] = cvtpk(a1.x, a1.y); kf0.u[3] = cvtpk(a1.z, a1.w);
        kf1.u[0] = cvtpk(b0.x, b0.y); kf1.u[1] = cvtpk(b0.z, b0.w);
        kf1.u[2] = cvtpk(b1.x, b1.y); kf1.u[3] = cvtpk(b1.z, b1.w);
        f32x4 s0 = __builtin_amdgcn_mfma_f32_16x16x32_bf16(
                       kf0.s8, qf, (f32x4){0.f,0.f,0.f,0.f}, 0, 0, 0);
        f32x4 s1 = __builtin_amdgcn_mfma_f32_16x16x32_bf16(
                       kf1.s8, qf, (f32x4){0.f,0.f,0.f,0.f}, 0, 0, 0);
        unsigned mdw0 = 0, mdw1 = 0;
        if (MASKED) {
            mdw0 = *(const unsigned*)(mrow + kb + g * 4);
            mdw1 = *(const unsigned*)(mrow + kb + 16 + g * 4);
        }
        float e0[4], e1[4];
        #pragma unroll
        for (int r = 0; r < 4; ++r) {
            const int key0 = kb + 4 * g + r;
            const int key1 = key0 + 16;
            float x0 = exp2f(s0[r]);             // log2e folded into qf scale
            float x1 = exp2f(s1[r]);
            bool ok0, ok1;
            if (MASKED) {
                ok0 = ((mdw0 >> (8 * r)) & 255u) == 0u;
                ok1 = ((mdw1 >> (8 * r)) & 255u) == 0u;
            } else {
                ok0 = (key0 >= LO) & (key0 < HI);
                ok1 = (key1 >= LO) & (key1 < HI);
            }
            e0[r] = ok0 ? x0 : 0.f;
            e1[r] = ok1 ? x1 : 0.f;
            ssum += e0[r] + e1[r];
        }
        unsigned w0 = cvtpk(e0[0], e0[1]), w1 = cvtpk(e0[2], e0[3]);
        unsigned w2 = cvtpk(e1[0], e1[1]), w3 = cvtpk(e1[2], e1[3]);
        int pA0 = __builtin_amdgcn_ds_bpermute(addrA, (int)w0);
        int pA1 = __builtin_amdgcn_ds_bpermute(addrA, (int)w1);
        int pB0 = __builtin_amdgcn_ds_bpermute(addrB, (int)w0);
        int pB1 = __builtin_amdgcn_ds_bpermute(addrB, (int)w1);
        int qA0 = __builtin_amdgcn_ds_bpermute(addrA, (int)w2);
        int qA1 = __builtin_amdgcn_ds_bpermute(addrA, (int)w3);
        int qB0 = __builtin_amdgcn_ds_bpermute(addrB, (int)w2);
        int qB1 = __builtin_amdgcn_ds_bpermute(addrB, (int)w3);
        union { int u[4]; short8 s8; } pf;
        pf.u[0] = sel ? pA0 : qA0;
        pf.u[1] = sel ? pA1 : qA1;
        pf.u[2] = sel ? pB0 : qB0;
        pf.u[3] = sel ? pB1 : qB1;
        short8 v0 = *(const short8*)(vlds + (size_t)qr * 976 + kb * 2 + g * 16);
        short8 v1 = *(const short8*)(vlds + (size_t)(qr + 16) * 976 + kb * 2 + g * 16);
        A0 = __builtin_amdgcn_mfma_f32_16x16x32_bf16(v0, pf.s8, A0, 0, 0, 0);
        A1 = __builtin_amdgcn_mfma_f32_16x16x32_bf16(v1, pf.s8, A1, 0, 0, 0);
    }
    ssum += __shfl_xor(ssum, 16);
    ssum += __shfl_xor(ssum, 32);
    const float inv = 1.f / ssum;
    O0 += A0 * inv;
    O1 += A1 * inv;
}

// ------------------------------------------------------------------
// MFMA attention: one block per (b,nh); 512 threads; ONLY V^T in LDS
// (31 KB). K frags read direct from global (L2). Forced <=64 VGPR.
// ------------------------------------------------------------------
__global__ __launch_bounds__(512, 8) void attn_mfma_kernel(
    const float* __restrict__ q4,
    const float* __restrict__ kg,  const float* __restrict__ vg,
    const float* __restrict__ kn,  const float* __restrict__ vn,
    const float* __restrict__ kv,  const float* __restrict__ vv,
    const float* __restrict__ kvn, const float* __restrict__ vvn,
    const unsigned char* __restrict__ maskp,
    float* __restrict__ ctx_out)
{
    __shared__ char vlds[32 * 976];     // V^T bf16 [32 d][480+pad keys]
    const int tid = threadIdx.x;
    const int bh = blockIdx.x, b = bh >> 4, nh = bh & 15;

    const float* vsrc[4] = { vg, vn, vv, vvn };
    const int rows[4] = { VN_, KNODE, KVEH, KVND };
    const int r0s[4]  = { 0, 224, 432, 456 };

    // ---- stage V^T bf16 [32][976B] with pair-writes; zero pad pairs ----
    for (int sI = 0; sI < 4; ++sI) {
        const float* sp = vsrc[sI] + (size_t)bh * rows[sI] * 32;
        const int PC = rows[sI] >> 1;
        for (int lin = tid; lin < PC * 32; lin += 512) {
            int p = lin >> 5, d = lin & 31;
            unsigned u = cvtpk(sp[(2 * p) * 32 + d], sp[(2 * p + 1) * 32 + d]);
            *(unsigned*)(vlds + (size_t)d * 976 + (size_t)(r0s[sI] + 2 * p) * 2) = u;
        }
        if ((rows[sI] & 1) && tid < 32) {
            int d = tid;
            unsigned u = cvtpk(sp[(rows[sI] - 1) * 32 + d], 0.f);
            *(unsigned*)(vlds + (size_t)d * 976 +
                         (size_t)(r0s[sI] + rows[sI] - 1) * 2) = u;
        }
    }
    for (int lin = tid; lin < 7 * 32; lin += 512) {
        int pi = lin >> 5, d = lin & 31;
        int pk = (pi == 0) ? 222 : (pi < 4) ? 424 + 2 * pi
               : (pi == 4) ? 454 : 466 + 2 * pi;
        *(unsigned*)(vlds + (size_t)d * 976 + (size_t)pk * 2) = 0;
    }
    __syncthreads();

    const int wave = tid >> 6;
    if (wave >= 7) return;                 // 7 q-tiles of 16 cover P=100
    const int g = (tid >> 4) & 3, qr = tid & 15;
    const int q0 = wave * 16;
    const int qe = (q0 + qr < 100) ? (q0 + qr) : 99;

    // Q frag, scale*log2(e) folded in (exp2 downstream)
    short8 qf;
    {
        const float* qp = q4 + ((size_t)bh * 100 + qe) * 32 + g * 8;
        float4 a = *(const float4*)qp;
        float4 c = *(const float4*)(qp + 4);
        const float SC = 0.2550524218f;    // 32^-.5 * log2(e)
        union { unsigned u[4]; short8 s8; } q;
        q.u[0] = cvtpk(a.x * SC, a.y * SC);
        q.u[1] = cvtpk(a.z * SC, a.w * SC);
        q.u[2] = cvtpk(c.x * SC, c.y * SC);
        q.u[3] = cvtpk(c.z * SC, c.w * SC);
        qf = q.s8;
    }
    const unsigned char* mrow = maskp + ((size_t)b * 100 + qe) * MASKP;
    const int addrA = 4 * (qr + ((g & 1) << 5));
    const int addrB = addrA + 64;

    // per-bh source base pointers (block-uniform -> SGPRs)
    const float* kgb  = kg  + (size_t)bh * VN_   * 32;
    const float* knb  = kn  + (size_t)bh * KNODE * 32;
    const float* kvb  = kv  + (size_t)bh * KVEH  * 32;
    const float* kvnb = kvn + (size_t)bh * KVND  * 32;

    f32x4 O0 = {0.f,0.f,0.f,0.f}, O1 = {0.f,0.f,0.f,0.f};
    attend_v4<true,  0,  6,   0, 224>(vlds, mrow, kgb, knb, kvb, kvnb,
                                      qf, g, qr, addrA, addrB, O0, O1);
    attend_v4<false, 7, 13, 224, 425>(vlds, mrow, kgb, knb, kvb, kvnb,
                                      qf, g, qr, addrA, addrB, O0, O1);
    attend_v4<false,13, 14, 432, 453>(vlds, mrow, kgb, knb, kvb, kvnb,
                                      qf, g, qr, addrA, addrB, O0, O1);
    attend_v4<false,14, 14, 456, 476>(vlds, mrow, kgb, knb, kvb, kvnb,
                                      qf, g, qr, addrA, addrB, O0, O1);

    if (q0 + qr < 100) {
        float* op = ctx_out + ((size_t)b * 100 + q0 + qr) * 512 + nh * 32 + 4 * g;
        *(f32x4*)op        = O0;
        *(f32x4*)(op + 16) = O1;
    }
}

// ------------------------------------------------------------------
// qproj MFMA: [25600,544pad] x Wq^T -> q4 [B,NH,P,HD]
// ------------------------------------------------------------------
__global__ __launch_bounds__(256) void qproj_mfma(
    const float* __restrict__ qg, const float* __restrict__ cf,
    const float* __restrict__ Wq, float* __restrict__ q4)
{
    __shared__ char As[64 * 80];
    __shared__ char Bs[64 * 80];
    const int tid = threadIdx.x;
    const int m0 = blockIdx.y * 64, n0 = blockIdx.x * 64;
    const int r = tid >> 2, s = tid & 3;
    const int wave = tid >> 6, lane = tid & 63;
    const int wm = wave >> 1, wn = wave & 1;
    const int g = lane >> 4, qr = lane & 15;

    f32x4 acc[2][2] = {};
    for (int k0 = 0; k0 < 544; k0 += 32) {
        const int k = k0 + 8 * s;
        uint4 wa = {0,0,0,0}, wb = {0,0,0,0};
        {
            float4 a = {0,0,0,0}, c = {0,0,0,0};
            const int row = m0 + r;
            if (k < 512) {
                a = *(const float4*)(qg + (size_t)row * 512 + k);
                c = *(const float4*)(qg + (size_t)row * 512 + k + 4);
            } else if (k < 528) {
                a = *(const float4*)(cf + (size_t)row * 16 + (k - 512));
                c = *(const float4*)(cf + (size_t)row * 16 + (k - 512) + 4);
            }
            wa.x = f2bf(a.x) | (f2bf(a.y) << 16);
            wa.y = f2bf(a.z) | (f2bf(a.w) << 16);
            wa.z = f2bf(c.x) | (f2bf(c.y) << 16);
            wa.w = f2bf(c.z) | (f2bf(c.w) << 16);
        }
        {
            float4 a = {0,0,0,0}, c = {0,0,0,0};
            const int row = n0 + r;
            if (k < 528) {
                a = *(const float4*)(Wq + (size_t)row * 528 + k);
                c = *(const float4*)(Wq + (size_t)row * 528 + k + 4);
            }
            wb.x = f2bf(a.x) | (f2bf(a.y) << 16);
            wb.y = f2bf(a.z) | (f2bf(a.w) << 16);
            wb.z = f2bf(c.x) | (f2bf(c.y) << 16);
            wb.w = f2bf(c.z) | (f2bf(c.w) << 16);
        }
        __syncthreads();
        *(uint4*)(As + r * 80 + s * 16) = wa;
        *(uint4*)(Bs + r * 80 + s * 16) = wb;
        __syncthreads();
        short8 a0 = *(const short8*)(As + (wm * 32 + qr) * 80 + g * 16);
        short8 a1 = *(const short8*)(As + (wm * 32 + 16 + qr) * 80 + g * 16);
        short8 b0 = *(const short8*)(Bs + (wn * 32 + qr) * 80 + g * 16);
        short8 b1 = *(const short8*)(Bs + (wn * 32 + 16 + qr) * 80 + g * 16);
        acc[0][0] = __builtin_amdgcn_mfma_f32_16x16x32_bf16(a0, b0, acc[0][0], 0, 0, 0);
        acc[0][1] = __builtin_amdgcn_mfma_f32_16x16x32_bf16(a0, b1, acc[0][1], 0, 0, 0);
        acc[1][0] = __builtin_amdgcn_mfma_f32_16x16x32_bf16(a1, b0, acc[1][0], 0, 0, 0);
        acc[1][1] = __builtin_amdgcn_mfma_f32_16x16x32_bf16(a1, b1, acc[1][1], 0, 0, 0);
    }
    #pragma unroll
    for (int mi = 0; mi < 2; ++mi)
        #pragma unroll
        for (int ni = 0; ni < 2; ++ni)
            #pragma unroll
            for (int reg = 0; reg < 4; ++reg) {
                int m = m0 + wm * 32 + 16 * mi + 4 * g + reg;
                int n = n0 + wn * 32 + 16 * ni + qr;
                int bb = m / 100, p = m - bb * 100;
                int nh = n >> 5, d = n & 31;
                q4[(((size_t)bb * NH_ + nh) * P_ + p) * HD_ + d] = acc[mi][ni][reg];
            }
}

// ------------------------------------------------------------------
// combine MFMA: [25600,512] x Wc^T + bias -> mha [25600,512]
// ------------------------------------------------------------------
__global__ __launch_bounds__(256) void combine_mfma(
    const float* __restrict__ ctx, const float* __restrict__ Wc,
    const float* __restrict__ bias, float* __restrict__ mha)
{
    __shared__ char As[64 * 80];
    __shared__ char Bs[64 * 80];
    const int tid = threadIdx.x;
    const int m0 = blockIdx.y * 64, n0 = blockIdx.x * 64;
    const int r = tid >> 2, s = tid & 3;
    const int wave = tid >> 6, lane = tid & 63;
    const int wm = wave >> 1, wn = wave & 1;
    const int g = lane >> 4, qr = lane & 15;

    f32x4 acc[2][2] = {};
    for (int k0 = 0; k0 < 512; k0 += 32) {
        const int k = k0 + 8 * s;
        float4 a = *(const float4*)(ctx + (size_t)(m0 + r) * 512 + k);
        float4 c = *(const float4*)(ctx + (size_t)(m0 + r) * 512 + k + 4);
        uint4 wa, wb;
        wa.x = f2bf(a.x) | (f2bf(a.y) << 16);
        wa.y = f2bf(a.z) | (f2bf(a.w) << 16);
        wa.z = f2bf(c.x) | (f2bf(c.y) << 16);
        wa.w = f2bf(c.z) | (f2bf(c.w) << 16);
        a = *(const float4*)(Wc + (size_t)(n0 + r) * 512 + k);
        c = *(const float4*)(Wc + (size_t)(n0 + r) * 512 + k + 4);
        wb.x = f2bf(a.x) | (f2bf(a.y) << 16);
        wb.y = f2bf(a.z) | (f2bf(a.w) << 16);
        wb.z = f2bf(c.x) | (f2bf(c.y) << 16);
        wb.w = f2bf(c.z) | (f2bf(c.w) << 16);
        __syncthreads();
        *(uint4*)(As + r * 80 + s * 16) = wa;
        *(uint4*)(Bs + r * 80 + s * 16) = wb;
        __syncthreads();
        short8 a0 = *(const short8*)(As + (wm * 32 + qr) * 80 + g * 16);
        short8 a1 = *(const short8*)(As + (wm * 32 + 16 + qr) * 80 + g * 16);
        short8 b0 = *(const short8*)(Bs + (wn * 32 + qr) * 80 + g * 16);
        short8 b1 = *(const short8*)(Bs + (wn * 32 + 16 + qr) * 80 + g * 16);
        acc[0][0] = __builtin_amdgcn_mfma_f32_16x16x32_bf16(a0, b0, acc[0][0], 0, 0, 0);
        acc[0][1] = __builtin_amdgcn_mfma_f32_16x16x32_bf16(a0, b1, acc[0][1], 0, 0, 0);
        acc[1][0] = __builtin_amdgcn_mfma_f32_16x16x32_bf16(a1, b0, acc[1][0], 0, 0, 0);
        acc[1][1] = __builtin_amdgcn_mfma_f32_16x16x32_bf16(a1, b1, acc[1][1], 0, 0, 0);
    }
    const float bia0 = bias[n0 + wn * 32 + qr];
    const float bia1 = bias[n0 + wn * 32 + 16 + qr];
    #pragma unroll
    for (int mi = 0; mi < 2; ++mi)
        #pragma unroll
        for (int ni = 0; ni < 2; ++ni)
            #pragma unroll
            for (int reg = 0; reg < 4; ++reg) {
                int m = m0 + wm * 32 + 16 * mi + 4 * g + reg;
                int n = n0 + wn * 32 + 16 * ni + qr;
                mha[(size_t)m * 512 + n] = acc[mi][ni][reg] + (ni ? bia1 : bia0);
            }
}

// ------------------------------------------------------------------
// logits MFMA: per b, out[p,key] = sum_h mha[b,p,h]*cp[b,h,key]
// ------------------------------------------------------------------
__global__ __launch_bounds__(512) void logits_mfma(
    const float* __restrict__ mha,   // [B*P, 512]
    const float* __restrict__ cp,    // [B, 512, VN]
    float* __restrict__ out)         // [B*P, VN]
{
    __shared__ char As[128 * 80];
    __shared__ char Bs[224 * 80];
    const int b = blockIdx.x;
    const int tid = threadIdx.x;
    const int wave = tid >> 6, lane = tid & 63;
    const int g = lane >> 4, qr = lane & 15;
    const int row = tid >> 2, s = tid & 3;

    f32x4 acc[14] = {};
    for (int h0 = 0; h0 < 512; h0 += 32) {
        uint4 wa = {0,0,0,0};
        if (row < 100) {
            const float* mp = mha + ((size_t)b * P_ + row) * 512 + h0 + 8 * s;
            float4 a = *(const float4*)mp;
            float4 c = *(const float4*)(mp + 4);
            wa.x = f2bf(a.x) | (f2bf(a.y) << 16);
            wa.y = f2bf(a.z) | (f2bf(a.w) << 16);
            wa.z = f2bf(c.x) | (f2bf(c.y) << 16);
            wa.w = f2bf(c.z) | (f2bf(c.w) << 16);
        }
        __syncthreads();
        *(uint4*)(As + row * 80 + s * 16) = wa;
        for (int lin = tid; lin < 224 * 8; lin += 512) {
            int kk = lin % 224, hq = lin / 224;
            int h = hq * 4;
            float v0 = 0.f, v1 = 0.f, v2 = 0.f, v3 = 0.f;
            if (kk < VN_) {
                const float* cpp = cp + ((size_t)b * 512 + h0 + h) * VN_ + kk;
                v0 = cpp[0]; v1 = cpp[VN_]; v2 = cpp[2 * VN_]; v3 = cpp[3 * VN_];
            }
            uint2 w;
            w.x = f2bf(v0) | (f2bf(v1) << 16);
            w.y = f2bf(v2) | (f2bf(v3) << 16);
            *(uint2*)(Bs + kk * 80 + h * 2) = w;
        }
        __syncthreads();
        short8 af = *(const short8*)(As + (wave * 16 + qr) * 80 + g * 16);
        #pragma unroll
        for (int ni = 0; ni < 14; ++ni) {
            short8 bf = *(const short8*)(Bs + (ni * 16 + qr) * 80 + g * 16);
            acc[ni] = __builtin_amdgcn_mfma_f32_16x16x32_bf16(af, bf, acc[ni], 0, 0, 0);
        }
    }
    #pragma unroll
    for (int ni = 0; ni < 14; ++ni) {
        int key = ni * 16 + qr;
        if (key >= VN_) continue;
        #pragma unroll
        for (int reg = 0; reg < 4; ++reg) {
            int p = wave * 16 + 4 * g + reg;
            if (p < P_)
                out[((size_t)b * P_ + p) * VN_ + key] = acc[ni][reg];
        }
    }
}

// ------------------------------------------------------------------
extern "C" void kernel_launch(void* const* d_in, const int* in_sizes, int n_in,
                              void* d_out, int out_size, void* d_ws, size_t ws_size,
                              hipStream_t stream) {
    const float* qg   = (const float*)d_in[0];
    const float* kgl  = (const float*)d_in[1];
    const float* vgl  = (const float*)d_in[2];
    const float* knd  = (const float*)d_in[3];
    const float* vnd  = (const float*)d_in[4];
    const float* kvh  = (const float*)d_in[5];
    const float* vvh  = (const float*)d_in[6];
    const float* kvnd = (const float*)d_in[7];
    const float* vvnd = (const float*)d_in[8];
    const float* cf   = (const float*)d_in[9];
    const float* cp   = (const float*)d_in[10];
    const void*  mask_raw = d_in[11];
    const float* Wq   = (const float*)d_in[12];
    const float* Wc   = (const float*)d_in[13];
    const float* bias = (const float*)d_in[14];
    float* out = (float*)d_out;

    const size_t NQ = (size_t)B_ * NH_ * P_ * HD_;   // 13,107,200 f32
    float* q4buf  = (float*)d_ws;
    float* ctxbuf = q4buf + NQ;
    float* mhabuf = q4buf;                            // reuse: q dead after attn
    unsigned char* mask8 = (unsigned char*)(ctxbuf + NQ);
    const int MASKN_P = B_ * P_ * MASKP;
    int* flag = (int*)(mask8 + ((MASKN_P + 15) & ~15));

    hipMemsetAsync(flag, 0, sizeof(int), stream);
    mask_detect_kernel<<<16, 256, 0, stream>>>(
        (const unsigned int*)mask_raw, 4096, flag);
    mask_repack_kernel<<<(MASKN_P + 255) / 256, 256, 0, stream>>>(
        (const unsigned char*)mask_raw, (const int*)mask_raw, flag, mask8);

    qproj_mfma<<<dim3(8, 400), 256, 0, stream>>>(qg, cf, Wq, q4buf);
    attn_mfma_kernel<<<B_ * NH_, 512, 0, stream>>>(
        q4buf, kgl, vgl, knd, vnd, kvh, vvh, kvnd, vvnd, mask8, ctxbuf);
    combine_mfma<<<dim3(8, 400), 256, 0, stream>>>(ctxbuf, Wc, bias, mhabuf);
    logits_mfma<<<B_, 512, 0, stream>>>(mhabuf, cp, out);
}

// Round 10
// 544.349 us; speedup vs baseline: 1.0565x; 1.0565x over previous
//
#include <hip/hip_runtime.h>
#include <hip/hip_bf16.h>

#define B_   256
#define P_   100
#define H_   512
#define NH_  16
#define HD_  32
#define VN_  221
#define KNODE 201
#define KVEH  21
#define KVND  20
#define CSD_ 16
#define MASKP 224                       // padded mask row stride (aligned dwords)

typedef __attribute__((ext_vector_type(8))) short short8;
typedef __attribute__((ext_vector_type(4))) float f32x4;

__device__ __forceinline__ unsigned cvtpk(float lo, float hi) {
    unsigned r;
    asm("v_cvt_pk_bf16_f32 %0, %1, %2" : "=v"(r) : "v"(lo), "v"(hi));
    return r;
}
__device__ __forceinline__ unsigned f2bf(float f) {
    union { float f; unsigned u; } x; x.f = f;
    return (x.u + 0x7FFFu + ((x.u >> 16) & 1u)) >> 16;   // RNE bf16 bits
}

// ------------------------------------------------------------------
// mask dtype probe + repack to padded [B*P][224] u8 (pad = 1 = illegal)
// ------------------------------------------------------------------
__global__ void mask_detect_kernel(const unsigned int* __restrict__ w,
                                   int nwords, int* __restrict__ flag) {
    int i = blockIdx.x * 256 + threadIdx.x;
    if (i < nwords && (w[i] & ~1u)) atomicOr(flag, 1);
}

__global__ void mask_repack_kernel(const unsigned char* __restrict__ mb,
                                   const int* __restrict__ mw,
                                   const int* __restrict__ flag,
                                   unsigned char* __restrict__ out) {
    int i = blockIdx.x * blockDim.x + threadIdx.x;
    if (i >= B_ * P_ * MASKP) return;
    int row = i / MASKP, k = i - row * MASKP;
    unsigned char v = 1;
    if (k < VN_) {
        int src = row * VN_ + k;
        v = (*flag) ? (unsigned char)(mb[src] != 0) : (unsigned char)(mw[src] != 0);
    }
    out[i] = v;
}

// ------------------------------------------------------------------
// concat-key -> clamped source row pointer (folds to 1 branch for
// interior chunks; clamped rows are valid memory, scores masked off)
// ------------------------------------------------------------------
__device__ __forceinline__ const float* krow(
    const float* __restrict__ kgb, const float* __restrict__ knb,
    const float* __restrict__ kvb, const float* __restrict__ kvnb, int key)
{
    if (key < 224) { int r = key < 220 ? key : 220; return kgb + r * 32; }
    if (key < 432) { int r = key - 224; r = r < 200 ? r : 200; return knb + r * 32; }
    if (key < 456) { int r = key - 432; r = r < 20 ? r : 20; return kvb + r * 32; }
    int r = key - 456; r = r < 19 ? r : 19; return kvnb + r * 32;
}

// ------------------------------------------------------------------
// one source: K-frags direct from global f32 (+cvtpk), QK MFMA, exp2,
// bpermute-gather P, PV MFMA from V^T LDS. Per-chunk.
// ------------------------------------------------------------------
template<bool MASKED, int C0, int C1, int LO, int HI>
__device__ __forceinline__ void attend_v4(
    const char* __restrict__ vlds,
    const unsigned char* __restrict__ mrow,
    const float* __restrict__ kgb, const float* __restrict__ knb,
    const float* __restrict__ kvb, const float* __restrict__ kvnb,
    short8 qf, int g, int qr, int addrA, int addrB,
    f32x4& O0, f32x4& O1)
{
    f32x4 A0 = {0.f,0.f,0.f,0.f}, A1 = {0.f,0.f,0.f,0.f};
    float ssum = 0.f;
    const bool sel = g < 2;
    #pragma unroll
    for (int c = C0; c <= C1; ++c) {
        const int kb = c * 32;
        const float* p0 = krow(kgb, knb, kvb, kvnb, kb + qr);
        const float* p1 = krow(kgb, knb, kvb, kvnb, kb + 16 + qr);
        float4 a0 = *(const float4*)(p0 + 8 * g);
        float4 a1 = *(const float4*)(p0 + 8 * g + 4);
        float4 b0 = *(const float4*)(p1 + 8 * g);
        float4 b1 = *(const float4*)(p1 + 8 * g + 4);
        union { unsigned u[4]; short8 s8; } kf0, kf1;
        kf0.u[0] = cvtpk(a0.x, a0.y); kf0.u[1] = cvtpk(a0.z, a0.w);
        kf0.u[2] = cvtpk(a1.x, a1.y); kf0.u[3] = cvtpk(a1.z, a1.w);
        kf1.u[0] = cvtpk(b0.x, b0.y); kf1.u[1] = cvtpk(b0.z, b0.w);
        kf1.u[2] = cvtpk(b1.x, b1.y); kf1.u[3] = cvtpk(b1.z, b1.w);
        f32x4 s0 = __builtin_amdgcn_mfma_f32_16x16x32_bf16(
                       kf0.s8, qf, (f32x4){0.f,0.f,0.f,0.f}, 0, 0, 0);
        f32x4 s1 = __builtin_amdgcn_mfma_f32_16x16x32_bf16(
                       kf1.s8, qf, (f32x4){0.f,0.f,0.f,0.f}, 0, 0, 0);
        unsigned mdw0 = 0, mdw1 = 0;
        if (MASKED) {
            mdw0 = *(const unsigned*)(mrow + kb + g * 4);
            mdw1 = *(const unsigned*)(mrow + kb + 16 + g * 4);
        }
        float e0[4], e1[4];
        #pragma unroll
        for (int r = 0; r < 4; ++r) {
            const int key0 = kb + 4 * g + r;
            const int key1 = key0 + 16;
            float x0 = exp2f(s0[r]);             // log2e folded into qf scale
            float x1 = exp2f(s1[r]);
            bool ok0, ok1;
            if (MASKED) {
                ok0 = ((mdw0 >> (8 * r)) & 255u) == 0u;
                ok1 = ((mdw1 >> (8 * r)) & 255u) == 0u;
            } else {
                ok0 = (key0 >= LO) & (key0 < HI);
                ok1 = (key1 >= LO) & (key1 < HI);
            }
            e0[r] = ok0 ? x0 : 0.f;
            e1[r] = ok1 ? x1 : 0.f;
            ssum += e0[r] + e1[r];
        }
        unsigned w0 = cvtpk(e0[0], e0[1]), w1 = cvtpk(e0[2], e0[3]);
        unsigned w2 = cvtpk(e1[0], e1[1]), w3 = cvtpk(e1[2], e1[3]);
        int pA0 = __builtin_amdgcn_ds_bpermute(addrA, (int)w0);
        int pA1 = __builtin_amdgcn_ds_bpermute(addrA, (int)w1);
        int pB0 = __builtin_amdgcn_ds_bpermute(addrB, (int)w0);
        int pB1 = __builtin_amdgcn_ds_bpermute(addrB, (int)w1);
        int qA0 = __builtin_amdgcn_ds_bpermute(addrA, (int)w2);
        int qA1 = __builtin_amdgcn_ds_bpermute(addrA, (int)w3);
        int qB0 = __builtin_amdgcn_ds_bpermute(addrB, (int)w2);
        int qB1 = __builtin_amdgcn_ds_bpermute(addrB, (int)w3);
        union { int u[4]; short8 s8; } pf;
        pf.u[0] = sel ? pA0 : qA0;
        pf.u[1] = sel ? pA1 : qA1;
        pf.u[2] = sel ? pB0 : qB0;
        pf.u[3] = sel ? pB1 : qB1;
        short8 v0 = *(const short8*)(vlds + (size_t)qr * 976 + kb * 2 + g * 16);
        short8 v1 = *(const short8*)(vlds + (size_t)(qr + 16) * 976 + kb * 2 + g * 16);
        A0 = __builtin_amdgcn_mfma_f32_16x16x32_bf16(v0, pf.s8, A0, 0, 0, 0);
        A1 = __builtin_amdgcn_mfma_f32_16x16x32_bf16(v1, pf.s8, A1, 0, 0, 0);
    }
    ssum += __shfl_xor(ssum, 16);
    ssum += __shfl_xor(ssum, 32);
    const float inv = 1.f / ssum;
    O0 += A0 * inv;
    O1 += A1 * inv;
}

// ------------------------------------------------------------------
// MFMA attention: one block per (b,nh); 512 threads; ONLY V^T in LDS
// (31 KB). K frags direct from global (L2). launch_bounds(512,4):
// 128-VGPR budget -> no spill (r8's 64-cap spilled ~37 regs = 314MB
// scratch traffic; r9's (512,6) miscompiled/NaN -> avoided).
// ------------------------------------------------------------------
__global__ __launch_bounds__(512, 4) void attn_mfma_kernel(
    const float* __restrict__ q4,
    const float* __restrict__ kg,  const float* __restrict__ vg,
    const float* __restrict__ kn,  const float* __restrict__ vn,
    const float* __restrict__ kv,  const float* __restrict__ vv,
    const float* __restrict__ kvn, const float* __restrict__ vvn,
    const unsigned char* __restrict__ maskp,
    float* __restrict__ ctx_out)
{
    __shared__ char vlds[32 * 976];     // V^T bf16 [32 d][480+pad keys]
    const int tid = threadIdx.x;
    const int bh = blockIdx.x, b = bh >> 4, nh = bh & 15;

    const float* vsrc[4] = { vg, vn, vv, vvn };
    const int rows[4] = { VN_, KNODE, KVEH, KVND };
    const int r0s[4]  = { 0, 224, 432, 456 };

    // ---- stage V^T bf16 [32][976B] with pair-writes; zero pad pairs ----
    for (int sI = 0; sI < 4; ++sI) {
        const float* sp = vsrc[sI] + (size_t)bh * rows[sI] * 32;
        const int PC = rows[sI] >> 1;
        for (int lin = tid; lin < PC * 32; lin += 512) {
            int p = lin >> 5, d = lin & 31;
            unsigned u = cvtpk(sp[(2 * p) * 32 + d], sp[(2 * p + 1) * 32 + d]);
            *(unsigned*)(vlds + (size_t)d * 976 + (size_t)(r0s[sI] + 2 * p) * 2) = u;
        }
        if ((rows[sI] & 1) && tid < 32) {
            int d = tid;
            unsigned u = cvtpk(sp[(rows[sI] - 1) * 32 + d], 0.f);
            *(unsigned*)(vlds + (size_t)d * 976 +
                         (size_t)(r0s[sI] + rows[sI] - 1) * 2) = u;
        }
    }
    for (int lin = tid; lin < 7 * 32; lin += 512) {
        int pi = lin >> 5, d = lin & 31;
        int pk = (pi == 0) ? 222 : (pi < 4) ? 424 + 2 * pi
               : (pi == 4) ? 454 : 466 + 2 * pi;
        *(unsigned*)(vlds + (size_t)d * 976 + (size_t)pk * 2) = 0;
    }
    __syncthreads();

    const int wave = tid >> 6;
    if (wave >= 7) return;                 // 7 q-tiles of 16 cover P=100
    const int g = (tid >> 4) & 3, qr = tid & 15;
    const int q0 = wave * 16;
    const int qe = (q0 + qr < 100) ? (q0 + qr) : 99;

    // Q frag, scale*log2(e) folded in (exp2 downstream)
    short8 qf;
    {
        const float* qp = q4 + ((size_t)bh * 100 + qe) * 32 + g * 8;
        float4 a = *(const float4*)qp;
        float4 c = *(const float4*)(qp + 4);
        const float SC = 0.2550524218f;    // 32^-.5 * log2(e)
        union { unsigned u[4]; short8 s8; } q;
        q.u[0] = cvtpk(a.x * SC, a.y * SC);
        q.u[1] = cvtpk(a.z * SC, a.w * SC);
        q.u[2] = cvtpk(c.x * SC, c.y * SC);
        q.u[3] = cvtpk(c.z * SC, c.w * SC);
        qf = q.s8;
    }
    const unsigned char* mrow = maskp + ((size_t)b * 100 + qe) * MASKP;
    const int addrA = 4 * (qr + ((g & 1) << 5));
    const int addrB = addrA + 64;

    // per-bh source base pointers (block-uniform -> SGPRs)
    const float* kgb  = kg  + (size_t)bh * VN_   * 32;
    const float* knb  = kn  + (size_t)bh * KNODE * 32;
    const float* kvb  = kv  + (size_t)bh * KVEH  * 32;
    const float* kvnb = kvn + (size_t)bh * KVND  * 32;

    f32x4 O0 = {0.f,0.f,0.f,0.f}, O1 = {0.f,0.f,0.f,0.f};
    attend_v4<true,  0,  6,   0, 224>(vlds, mrow, kgb, knb, kvb, kvnb,
                                      qf, g, qr, addrA, addrB, O0, O1);
    attend_v4<false, 7, 13, 224, 425>(vlds, mrow, kgb, knb, kvb, kvnb,
                                      qf, g, qr, addrA, addrB, O0, O1);
    attend_v4<false,13, 14, 432, 453>(vlds, mrow, kgb, knb, kvb, kvnb,
                                      qf, g, qr, addrA, addrB, O0, O1);
    attend_v4<false,14, 14, 456, 476>(vlds, mrow, kgb, knb, kvb, kvnb,
                                      qf, g, qr, addrA, addrB, O0, O1);

    if (q0 + qr < 100) {
        float* op = ctx_out + ((size_t)b * 100 + q0 + qr) * 512 + nh * 32 + 4 * g;
        *(f32x4*)op        = O0;
        *(f32x4*)(op + 16) = O1;
    }
}

// ------------------------------------------------------------------
// qproj MFMA: [25600,544pad] x Wq^T -> q4 [B,NH,P,HD]
// ------------------------------------------------------------------
__global__ __launch_bounds__(256) void qproj_mfma(
    const float* __restrict__ qg, const float* __restrict__ cf,
    const float* __restrict__ Wq, float* __restrict__ q4)
{
    __shared__ char As[64 * 80];
    __shared__ char Bs[64 * 80];
    const int tid = threadIdx.x;
    const int m0 = blockIdx.y * 64, n0 = blockIdx.x * 64;
    const int r = tid >> 2, s = tid & 3;
    const int wave = tid >> 6, lane = tid & 63;
    const int wm = wave >> 1, wn = wave & 1;
    const int g = lane >> 4, qr = lane & 15;

    f32x4 acc[2][2] = {};
    for (int k0 = 0; k0 < 544; k0 += 32) {
        const int k = k0 + 8 * s;
        uint4 wa = {0,0,0,0}, wb = {0,0,0,0};
        {
            float4 a = {0,0,0,0}, c = {0,0,0,0};
            const int row = m0 + r;
            if (k < 512) {
                a = *(const float4*)(qg + (size_t)row * 512 + k);
                c = *(const float4*)(qg + (size_t)row * 512 + k + 4);
            } else if (k < 528) {
                a = *(const float4*)(cf + (size_t)row * 16 + (k - 512));
                c = *(const float4*)(cf + (size_t)row * 16 + (k - 512) + 4);
            }
            wa.x = f2bf(a.x) | (f2bf(a.y) << 16);
            wa.y = f2bf(a.z) | (f2bf(a.w) << 16);
            wa.z = f2bf(c.x) | (f2bf(c.y) << 16);
            wa.w = f2bf(c.z) | (f2bf(c.w) << 16);
        }
        {
            float4 a = {0,0,0,0}, c = {0,0,0,0};
            const int row = n0 + r;
            if (k < 528) {
                a = *(const float4*)(Wq + (size_t)row * 528 + k);
                c = *(const float4*)(Wq + (size_t)row * 528 + k + 4);
            }
            wb.x = f2bf(a.x) | (f2bf(a.y) << 16);
            wb.y = f2bf(a.z) | (f2bf(a.w) << 16);
            wb.z = f2bf(c.x) | (f2bf(c.y) << 16);
            wb.w = f2bf(c.z) | (f2bf(c.w) << 16);
        }
        __syncthreads();
        *(uint4*)(As + r * 80 + s * 16) = wa;
        *(uint4*)(Bs + r * 80 + s * 16) = wb;
        __syncthreads();
        short8 a0 = *(const short8*)(As + (wm * 32 + qr) * 80 + g * 16);
        short8 a1 = *(const short8*)(As + (wm * 32 + 16 + qr) * 80 + g * 16);
        short8 b0 = *(const short8*)(Bs + (wn * 32 + qr) * 80 + g * 16);
        short8 b1 = *(const short8*)(Bs + (wn * 32 + 16 + qr) * 80 + g * 16);
        acc[0][0] = __builtin_amdgcn_mfma_f32_16x16x32_bf16(a0, b0, acc[0][0], 0, 0, 0);
        acc[0][1] = __builtin_amdgcn_mfma_f32_16x16x32_bf16(a0, b1, acc[0][1], 0, 0, 0);
        acc[1][0] = __builtin_amdgcn_mfma_f32_16x16x32_bf16(a1, b0, acc[1][0], 0, 0, 0);
        acc[1][1] = __builtin_amdgcn_mfma_f32_16x16x32_bf16(a1, b1, acc[1][1], 0, 0, 0);
    }
    #pragma unroll
    for (int mi = 0; mi < 2; ++mi)
        #pragma unroll
        for (int ni = 0; ni < 2; ++ni)
            #pragma unroll
            for (int reg = 0; reg < 4; ++reg) {
                int m = m0 + wm * 32 + 16 * mi + 4 * g + reg;
                int n = n0 + wn * 32 + 16 * ni + qr;
                int bb = m / 100, p = m - bb * 100;
                int nh = n >> 5, d = n & 31;
                q4[(((size_t)bb * NH_ + nh) * P_ + p) * HD_ + d] = acc[mi][ni][reg];
            }
}

// ------------------------------------------------------------------
// combine MFMA: [25600,512] x Wc^T + bias -> mha [25600,512]
// ------------------------------------------------------------------
__global__ __launch_bounds__(256) void combine_mfma(
    const float* __restrict__ ctx, const float* __restrict__ Wc,
    const float* __restrict__ bias, float* __restrict__ mha)
{
    __shared__ char As[64 * 80];
    __shared__ char Bs[64 * 80];
    const int tid = threadIdx.x;
    const int m0 = blockIdx.y * 64, n0 = blockIdx.x * 64;
    const int r = tid >> 2, s = tid & 3;
    const int wave = tid >> 6, lane = tid & 63;
    const int wm = wave >> 1, wn = wave & 1;
    const int g = lane >> 4, qr = lane & 15;

    f32x4 acc[2][2] = {};
    for (int k0 = 0; k0 < 512; k0 += 32) {
        const int k = k0 + 8 * s;
        float4 a = *(const float4*)(ctx + (size_t)(m0 + r) * 512 + k);
        float4 c = *(const float4*)(ctx + (size_t)(m0 + r) * 512 + k + 4);
        uint4 wa, wb;
        wa.x = f2bf(a.x) | (f2bf(a.y) << 16);
        wa.y = f2bf(a.z) | (f2bf(a.w) << 16);
        wa.z = f2bf(c.x) | (f2bf(c.y) << 16);
        wa.w = f2bf(c.z) | (f2bf(c.w) << 16);
        a = *(const float4*)(Wc + (size_t)(n0 + r) * 512 + k);
        c = *(const float4*)(Wc + (size_t)(n0 + r) * 512 + k + 4);
        wb.x = f2bf(a.x) | (f2bf(a.y) << 16);
        wb.y = f2bf(a.z) | (f2bf(a.w) << 16);
        wb.z = f2bf(c.x) | (f2bf(c.y) << 16);
        wb.w = f2bf(c.z) | (f2bf(c.w) << 16);
        __syncthreads();
        *(uint4*)(As + r * 80 + s * 16) = wa;
        *(uint4*)(Bs + r * 80 + s * 16) = wb;
        __syncthreads();
        short8 a0 = *(const short8*)(As + (wm * 32 + qr) * 80 + g * 16);
        short8 a1 = *(const short8*)(As + (wm * 32 + 16 + qr) * 80 + g * 16);
        short8 b0 = *(const short8*)(Bs + (wn * 32 + qr) * 80 + g * 16);
        short8 b1 = *(const short8*)(Bs + (wn * 32 + 16 + qr) * 80 + g * 16);
        acc[0][0] = __builtin_amdgcn_mfma_f32_16x16x32_bf16(a0, b0, acc[0][0], 0, 0, 0);
        acc[0][1] = __builtin_amdgcn_mfma_f32_16x16x32_bf16(a0, b1, acc[0][1], 0, 0, 0);
        acc[1][0] = __builtin_amdgcn_mfma_f32_16x16x32_bf16(a1, b0, acc[1][0], 0, 0, 0);
        acc[1][1] = __builtin_amdgcn_mfma_f32_16x16x32_bf16(a1, b1, acc[1][1], 0, 0, 0);
    }
    const float bia0 = bias[n0 + wn * 32 + qr];
    const float bia1 = bias[n0 + wn * 32 + 16 + qr];
    #pragma unroll
    for (int mi = 0; mi < 2; ++mi)
        #pragma unroll
        for (int ni = 0; ni < 2; ++ni)
            #pragma unroll
            for (int reg = 0; reg < 4; ++reg) {
                int m = m0 + wm * 32 + 16 * mi + 4 * g + reg;
                int n = n0 + wn * 32 + 16 * ni + qr;
                mha[(size_t)m * 512 + n] = acc[mi][ni][reg] + (ni ? bia1 : bia0);
            }
}

// ------------------------------------------------------------------
// logits MFMA: per b, out[p,key] = sum_h mha[b,p,h]*cp[b,h,key]
// ------------------------------------------------------------------
__global__ __launch_bounds__(512) void logits_mfma(
    const float* __restrict__ mha,   // [B*P, 512]
    const float* __restrict__ cp,    // [B, 512, VN]
    float* __restrict__ out)         // [B*P, VN]
{
    __shared__ char As[128 * 80];
    __shared__ char Bs[224 * 80];
    const int b = blockIdx.x;
    const int tid = threadIdx.x;
    const int wave = tid >> 6, lane = tid & 63;
    const int g = lane >> 4, qr = lane & 15;
    const int row = tid >> 2, s = tid & 3;

    f32x4 acc[14] = {};
    for (int h0 = 0; h0 < 512; h0 += 32) {
        uint4 wa = {0,0,0,0};
        if (row < 100) {
            const float* mp = mha + ((size_t)b * P_ + row) * 512 + h0 + 8 * s;
            float4 a = *(const float4*)mp;
            float4 c = *(const float4*)(mp + 4);
            wa.x = f2bf(a.x) | (f2bf(a.y) << 16);
            wa.y = f2bf(a.z) | (f2bf(a.w) << 16);
            wa.z = f2bf(c.x) | (f2bf(c.y) << 16);
            wa.w = f2bf(c.z) | (f2bf(c.w) << 16);
        }
        __syncthreads();
        *(uint4*)(As + row * 80 + s * 16) = wa;
        for (int lin = tid; lin < 224 * 8; lin += 512) {
            int kk = lin % 224, hq = lin / 224;
            int h = hq * 4;
            float v0 = 0.f, v1 = 0.f, v2 = 0.f, v3 = 0.f;
            if (kk < VN_) {
                const float* cpp = cp + ((size_t)b * 512 + h0 + h) * VN_ + kk;
                v0 = cpp[0]; v1 = cpp[VN_]; v2 = cpp[2 * VN_]; v3 = cpp[3 * VN_];
            }
            uint2 w;
            w.x = f2bf(v0) | (f2bf(v1) << 16);
            w.y = f2bf(v2) | (f2bf(v3) << 16);
            *(uint2*)(Bs + kk * 80 + h * 2) = w;
        }
        __syncthreads();
        short8 af = *(const short8*)(As + (wave * 16 + qr) * 80 + g * 16);
        #pragma unroll
        for (int ni = 0; ni < 14; ++ni) {
            short8 bf = *(const short8*)(Bs + (ni * 16 + qr) * 80 + g * 16);
            acc[ni] = __builtin_amdgcn_mfma_f32_16x16x32_bf16(af, bf, acc[ni], 0, 0, 0);
        }
    }
    #pragma unroll
    for (int ni = 0; ni < 14; ++ni) {
        int key = ni * 16 + qr;
        if (key >= VN_) continue;
        #pragma unroll
        for (int reg = 0; reg < 4; ++reg) {
            int p = wave * 16 + 4 * g + reg;
            if (p < P_)
                out[((size_t)b * P_ + p) * VN_ + key] = acc[ni][reg];
        }
    }
}

// ------------------------------------------------------------------
extern "C" void kernel_launch(void* const* d_in, const int* in_sizes, int n_in,
                              void* d_out, int out_size, void* d_ws, size_t ws_size,
                              hipStream_t stream) {
    const float* qg   = (const float*)d_in[0];
    const float* kgl  = (const float*)d_in[1];
    const float* vgl  = (const float*)d_in[2];
    const float* knd  = (const float*)d_in[3];
    const float* vnd  = (const float*)d_in[4];
    const float* kvh  = (const float*)d_in[5];
    const float* vvh  = (const float*)d_in[6];
    const float* kvnd = (const float*)d_in[7];
    const float* vvnd = (const float*)d_in[8];
    const float* cf   = (const float*)d_in[9];
    const float* cp   = (const float*)d_in[10];
    const void*  mask_raw = d_in[11];
    const float* Wq   = (const float*)d_in[12];
    const float* Wc   = (const float*)d_in[13];
    const float* bias = (const float*)d_in[14];
    float* out = (float*)d_out;

    const size_t NQ = (size_t)B_ * NH_ * P_ * HD_;   // 13,107,200 f32
    float* q4buf  = (float*)d_ws;
    float* ctxbuf = q4buf + NQ;
    float* mhabuf = q4buf;                            // reuse: q dead after attn
    unsigned char* mask8 = (unsigned char*)(ctxbuf + NQ);
    const int MASKN_P = B_ * P_ * MASKP;
    int* flag = (int*)(mask8 + ((MASKN_P + 15) & ~15));

    hipMemsetAsync(flag, 0, sizeof(int), stream);
    mask_detect_kernel<<<16, 256, 0, stream>>>(
        (const unsigned int*)mask_raw, 4096, flag);
    mask_repack_kernel<<<(MASKN_P + 255) / 256, 256, 0, stream>>>(
        (const unsigned char*)mask_raw, (const int*)mask_raw, flag, mask8);

    qproj_mfma<<<dim3(8, 400), 256, 0, stream>>>(qg, cf, Wq, q4buf);
    attn_mfma_kernel<<<B_ * NH_, 512, 0, stream>>>(
        q4buf, kgl, vgl, knd, vnd, kvh, vvh, kvnd, vvnd, mask8, ctxbuf);
    combine_mfma<<<dim3(8, 400), 256, 0, stream>>>(ctxbuf, Wc, bias, mhabuf);
    logits_mfma<<<B_, 512, 0, stream>>>(mhabuf, cp, out);
}

// Round 11
// 446.476 us; speedup vs baseline: 1.2881x; 1.2192x over previous
//
#include <hip/hip_runtime.h>
#include <hip/hip_bf16.h>

#define B_   256
#define P_   100
#define H_   512
#define NH_  16
#define HD_  32
#define VN_  221
#define KNODE 201
#define KVEH  21
#define KVND  20
#define CSD_ 16
#define MASKP 224                       // padded mask row stride (aligned dwords)

typedef __attribute__((ext_vector_type(8))) short short8;
typedef __attribute__((ext_vector_type(4))) float f32x4;

// ---- attention LDS layout (bytes) ----
// K   : 480 rows x 80B  (32 bf16 + 16B pad; 16B-stride 5 odd -> benign)   [0, 38400)
// V^T : 32 rows  x 976B (480 keys bf16; 16B-stride 61 odd)                [38400, 69632)
#define K_OFF   0
#define V_OFF   38400
#define ATTN_LDS_B 69632

__device__ __forceinline__ unsigned cvtpk(float lo, float hi) {
    unsigned r;
    asm("v_cvt_pk_bf16_f32 %0, %1, %2" : "=v"(r) : "v"(lo), "v"(hi));
    return r;
}
__device__ __forceinline__ unsigned f2bf(float f) {
    union { float f; unsigned u; } x; x.f = f;
    return (x.u + 0x7FFFu + ((x.u >> 16) & 1u)) >> 16;   // RNE bf16 bits
}

// ------------------------------------------------------------------
// mask dtype probe + repack to padded [B*P][224] u8 (pad = 1 = illegal)
// ------------------------------------------------------------------
__global__ void mask_detect_kernel(const unsigned int* __restrict__ w,
                                   int nwords, int* __restrict__ flag) {
    int i = blockIdx.x * 256 + threadIdx.x;
    if (i < nwords && (w[i] & ~1u)) atomicOr(flag, 1);
}

__global__ void mask_repack_kernel(const unsigned char* __restrict__ mb,
                                   const int* __restrict__ mw,
                                   const int* __restrict__ flag,
                                   unsigned char* __restrict__ out) {
    int i = blockIdx.x * blockDim.x + threadIdx.x;
    if (i >= B_ * P_ * MASKP) return;
    int row = i / MASKP, k = i - row * MASKP;
    unsigned char v = 1;
    if (k < VN_) {
        int src = row * VN_ + k;
        v = (*flag) ? (unsigned char)(mb[src] != 0) : (unsigned char)(mw[src] != 0);
    }
    out[i] = v;
}

// ------------------------------------------------------------------
// one source: QK MFMA, exp2, bpermute-gather P, PV MFMA.
// Mask dwords pre-fetched to registers (mpre) -> no global loads in chain.
// setprio(1) around MFMA clusters (T5). 2-way PV accumulator split.
// ------------------------------------------------------------------
template<bool MASKED, int C0, int C1, int LO, int HI>
__device__ __forceinline__ void attend_v5(
    const char* __restrict__ ldsb,
    const unsigned* __restrict__ mpre,
    short8 qf, int g, int qr, int addrA, int addrB,
    f32x4& O0, f32x4& O1)
{
    f32x4 A0a = {0.f,0.f,0.f,0.f}, A1a = {0.f,0.f,0.f,0.f};
    f32x4 A0b = {0.f,0.f,0.f,0.f}, A1b = {0.f,0.f,0.f,0.f};
    float ssum = 0.f;
    const bool sel = g < 2;
    #pragma unroll
    for (int c = C0; c <= C1; ++c) {
        const int kb = c * 32;
        short8 kf0 = *(const short8*)(ldsb + K_OFF + (size_t)(kb + qr) * 80 + g * 16);
        short8 kf1 = *(const short8*)(ldsb + K_OFF + (size_t)(kb + 16 + qr) * 80 + g * 16);
        __builtin_amdgcn_s_setprio(1);
        f32x4 s0 = __builtin_amdgcn_mfma_f32_16x16x32_bf16(
                       kf0, qf, (f32x4){0.f,0.f,0.f,0.f}, 0, 0, 0);
        f32x4 s1 = __builtin_amdgcn_mfma_f32_16x16x32_bf16(
                       kf1, qf, (f32x4){0.f,0.f,0.f,0.f}, 0, 0, 0);
        __builtin_amdgcn_s_setprio(0);
        unsigned mdw0 = 0, mdw1 = 0;
        if (MASKED) {
            mdw0 = mpre[2 * (c - C0)];
            mdw1 = mpre[2 * (c - C0) + 1];
        }
        float e0[4], e1[4];
        #pragma unroll
        for (int r = 0; r < 4; ++r) {
            const int key0 = kb + 4 * g + r;
            const int key1 = key0 + 16;
            float x0 = exp2f(s0[r]);             // log2e folded into qf scale
            float x1 = exp2f(s1[r]);
            bool ok0, ok1;
            if (MASKED) {
                ok0 = ((mdw0 >> (8 * r)) & 255u) == 0u;
                ok1 = ((mdw1 >> (8 * r)) & 255u) == 0u;
            } else {
                ok0 = (key0 >= LO) & (key0 < HI);
                ok1 = (key1 >= LO) & (key1 < HI);
            }
            e0[r] = ok0 ? x0 : 0.f;
            e1[r] = ok1 ? x1 : 0.f;
            ssum += e0[r] + e1[r];
        }
        unsigned w0 = cvtpk(e0[0], e0[1]), w1 = cvtpk(e0[2], e0[3]);
        unsigned w2 = cvtpk(e1[0], e1[1]), w3 = cvtpk(e1[2], e1[3]);
        int pA0 = __builtin_amdgcn_ds_bpermute(addrA, (int)w0);
        int pA1 = __builtin_amdgcn_ds_bpermute(addrA, (int)w1);
        int pB0 = __builtin_amdgcn_ds_bpermute(addrB, (int)w0);
        int pB1 = __builtin_amdgcn_ds_bpermute(addrB, (int)w1);
        int qA0 = __builtin_amdgcn_ds_bpermute(addrA, (int)w2);
        int qA1 = __builtin_amdgcn_ds_bpermute(addrA, (int)w3);
        int qB0 = __builtin_amdgcn_ds_bpermute(addrB, (int)w2);
        int qB1 = __builtin_amdgcn_ds_bpermute(addrB, (int)w3);
        union { int u[4]; short8 s8; } pf;
        pf.u[0] = sel ? pA0 : qA0;
        pf.u[1] = sel ? pA1 : qA1;
        pf.u[2] = sel ? pB0 : qB0;
        pf.u[3] = sel ? pB1 : qB1;
        short8 v0 = *(const short8*)(ldsb + V_OFF + (size_t)qr * 976 + kb * 2 + g * 16);
        short8 v1 = *(const short8*)(ldsb + V_OFF + (size_t)(qr + 16) * 976 + kb * 2 + g * 16);
        __builtin_amdgcn_s_setprio(1);
        if (c & 1) {
            A0b = __builtin_amdgcn_mfma_f32_16x16x32_bf16(v0, pf.s8, A0b, 0, 0, 0);
            A1b = __builtin_amdgcn_mfma_f32_16x16x32_bf16(v1, pf.s8, A1b, 0, 0, 0);
        } else {
            A0a = __builtin_amdgcn_mfma_f32_16x16x32_bf16(v0, pf.s8, A0a, 0, 0, 0);
            A1a = __builtin_amdgcn_mfma_f32_16x16x32_bf16(v1, pf.s8, A1a, 0, 0, 0);
        }
        __builtin_amdgcn_s_setprio(0);
    }
    ssum += __shfl_xor(ssum, 16);
    ssum += __shfl_xor(ssum, 32);
    const float inv = 1.f / ssum;
    O0 += (A0a + A0b) * inv;
    O1 += (A1a + A1b) * inv;
}

// ------------------------------------------------------------------
// MFMA attention: one block per (b,nh); 512 threads; K/V^T bf16 in LDS
// (r7 structure: best measured 267us). Q + mask prefetched before
// staging so their HBM latency hides under the staging phase.
// ------------------------------------------------------------------
__global__ __launch_bounds__(512, 4) void attn_mfma_kernel(
    const float* __restrict__ q4,
    const float* __restrict__ kg,  const float* __restrict__ vg,
    const float* __restrict__ kn,  const float* __restrict__ vn,
    const float* __restrict__ kv,  const float* __restrict__ vv,
    const float* __restrict__ kvn, const float* __restrict__ vvn,
    const unsigned char* __restrict__ maskp,
    float* __restrict__ ctx_out)
{
    extern __shared__ char ldsb[];
    const int tid = threadIdx.x;
    const int bh = blockIdx.x, b = bh >> 4, nh = bh & 15;

    // ---- early per-wave state + prefetch (latency hides under staging) ----
    const int wave = tid >> 6;
    const int g = (tid >> 4) & 3, qr = tid & 15;
    const int q0 = wave * 16;
    const int qe = (q0 + qr < 100) ? (q0 + qr) : 99;   // valid addr for all waves
    const float* qp = q4 + ((size_t)bh * 100 + qe) * 32 + g * 8;
    float4 qa = *(const float4*)qp;
    float4 qc = *(const float4*)(qp + 4);
    const unsigned char* mrow = maskp + ((size_t)b * 100 + qe) * MASKP;
    unsigned mpre[14];
    #pragma unroll
    for (int c = 0; c < 7; ++c) {
        mpre[2 * c]     = *(const unsigned*)(mrow + c * 32 + g * 4);
        mpre[2 * c + 1] = *(const unsigned*)(mrow + c * 32 + 16 + g * 4);
    }

    const float* ksrc[4] = { kg, kn, kv, kvn };
    const float* vsrc[4] = { vg, vn, vv, vvn };
    const int rows[4] = { VN_, KNODE, KVEH, KVND };
    const int r0s[4]  = { 0, 224, 432, 456 };

    // ---- stage K as bf16 [480 rows][80B], zero pad rows ----
    for (int sI = 0; sI < 4; ++sI) {
        const float* sp = ksrc[sI] + (size_t)bh * rows[sI] * 32;
        const int nslot = rows[sI] * 4;
        for (int lin = tid; lin < nslot; lin += 512) {
            int r = lin >> 2, s = lin & 3;
            float4 a = *(const float4*)(sp + r * 32 + s * 8);
            float4 c = *(const float4*)(sp + r * 32 + s * 8 + 4);
            uint4 w;
            w.x = cvtpk(a.x, a.y); w.y = cvtpk(a.z, a.w);
            w.z = cvtpk(c.x, c.y); w.w = cvtpk(c.z, c.w);
            *(uint4*)(ldsb + K_OFF + (size_t)(r0s[sI] + r) * 80 + s * 16) = w;
        }
    }
    for (int lin = tid; lin < 17 * 4; lin += 512) {
        int zi = lin >> 2, s = lin & 3;
        int zr = (zi < 3) ? 221 + zi : (zi < 10) ? 422 + zi
               : (zi < 13) ? 443 + zi : 463 + zi;
        *(uint4*)(ldsb + K_OFF + (size_t)zr * 80 + s * 16) = (uint4){0,0,0,0};
    }
    // ---- stage V^T bf16 [32][976B] with pair-writes; zero pad pairs ----
    {
        char* vb = ldsb + V_OFF;
        for (int sI = 0; sI < 4; ++sI) {
            const float* sp = vsrc[sI] + (size_t)bh * rows[sI] * 32;
            const int PC = rows[sI] >> 1;
            for (int lin = tid; lin < PC * 32; lin += 512) {
                int p = lin >> 5, d = lin & 31;
                unsigned u = cvtpk(sp[(2 * p) * 32 + d], sp[(2 * p + 1) * 32 + d]);
                *(unsigned*)(vb + (size_t)d * 976 + (size_t)(r0s[sI] + 2 * p) * 2) = u;
            }
            if ((rows[sI] & 1) && tid < 32) {
                int d = tid;
                unsigned u = cvtpk(sp[(rows[sI] - 1) * 32 + d], 0.f);
                *(unsigned*)(vb + (size_t)d * 976 +
                             (size_t)(r0s[sI] + rows[sI] - 1) * 2) = u;
            }
        }
        for (int lin = tid; lin < 7 * 32; lin += 512) {
            int pi = lin >> 5, d = lin & 31;
            int pk = (pi == 0) ? 222 : (pi < 4) ? 424 + 2 * pi
                   : (pi == 4) ? 454 : 466 + 2 * pi;
            *(unsigned*)(vb + (size_t)d * 976 + (size_t)pk * 2) = 0;
        }
    }
    __syncthreads();

    if (wave >= 7) return;                 // 7 q-tiles of 16 cover P=100

    // Q frag, scale*log2(e) folded in (exp2 downstream)
    short8 qf;
    {
        const float SC = 0.2550524218f;    // 32^-.5 * log2(e)
        union { unsigned u[4]; short8 s8; } q;
        q.u[0] = cvtpk(qa.x * SC, qa.y * SC);
        q.u[1] = cvtpk(qa.z * SC, qa.w * SC);
        q.u[2] = cvtpk(qc.x * SC, qc.y * SC);
        q.u[3] = cvtpk(qc.z * SC, qc.w * SC);
        qf = q.s8;
    }
    const int addrA = 4 * (qr + ((g & 1) << 5));
    const int addrB = addrA + 64;

    f32x4 O0 = {0.f,0.f,0.f,0.f}, O1 = {0.f,0.f,0.f,0.f};
    attend_v5<true,  0,  6,   0, 224>(ldsb, mpre, qf, g, qr, addrA, addrB, O0, O1);
    attend_v5<false, 7, 13, 224, 425>(ldsb, nullptr, qf, g, qr, addrA, addrB, O0, O1);
    attend_v5<false,13, 14, 432, 453>(ldsb, nullptr, qf, g, qr, addrA, addrB, O0, O1);
    attend_v5<false,14, 14, 456, 476>(ldsb, nullptr, qf, g, qr, addrA, addrB, O0, O1);

    if (q0 + qr < 100) {
        float* op = ctx_out + ((size_t)b * 100 + q0 + qr) * 512 + nh * 32 + 4 * g;
        *(f32x4*)op        = O0;
        *(f32x4*)(op + 16) = O1;
    }
}

// ------------------------------------------------------------------
// qproj MFMA: [25600,544pad] x Wq^T -> q4 [B,NH,P,HD]
// ------------------------------------------------------------------
__global__ __launch_bounds__(256) void qproj_mfma(
    const float* __restrict__ qg, const float* __restrict__ cf,
    const float* __restrict__ Wq, float* __restrict__ q4)
{
    __shared__ char As[64 * 80];
    __shared__ char Bs[64 * 80];
    const int tid = threadIdx.x;
    const int m0 = blockIdx.y * 64, n0 = blockIdx.x * 64;
    const int r = tid >> 2, s = tid & 3;
    const int wave = tid >> 6, lane = tid & 63;
    const int wm = wave >> 1, wn = wave & 1;
    const int g = lane >> 4, qr = lane & 15;

    f32x4 acc[2][2] = {};
    for (int k0 = 0; k0 < 544; k0 += 32) {
        const int k = k0 + 8 * s;
        uint4 wa = {0,0,0,0}, wb = {0,0,0,0};
        {
            float4 a = {0,0,0,0}, c = {0,0,0,0};
            const int row = m0 + r;
            if (k < 512) {
                a = *(const float4*)(qg + (size_t)row * 512 + k);
                c = *(const float4*)(qg + (size_t)row * 512 + k + 4);
            } else if (k < 528) {
                a = *(const float4*)(cf + (size_t)row * 16 + (k - 512));
                c = *(const float4*)(cf + (size_t)row * 16 + (k - 512) + 4);
            }
            wa.x = f2bf(a.x) | (f2bf(a.y) << 16);
            wa.y = f2bf(a.z) | (f2bf(a.w) << 16);
            wa.z = f2bf(c.x) | (f2bf(c.y) << 16);
            wa.w = f2bf(c.z) | (f2bf(c.w) << 16);
        }
        {
            float4 a = {0,0,0,0}, c = {0,0,0,0};
            const int row = n0 + r;
            if (k < 528) {
                a = *(const float4*)(Wq + (size_t)row * 528 + k);
                c = *(const float4*)(Wq + (size_t)row * 528 + k + 4);
            }
            wb.x = f2bf(a.x) | (f2bf(a.y) << 16);
            wb.y = f2bf(a.z) | (f2bf(a.w) << 16);
            wb.z = f2bf(c.x) | (f2bf(c.y) << 16);
            wb.w = f2bf(c.z) | (f2bf(c.w) << 16);
        }
        __syncthreads();
        *(uint4*)(As + r * 80 + s * 16) = wa;
        *(uint4*)(Bs + r * 80 + s * 16) = wb;
        __syncthreads();
        short8 a0 = *(const short8*)(As + (wm * 32 + qr) * 80 + g * 16);
        short8 a1 = *(const short8*)(As + (wm * 32 + 16 + qr) * 80 + g * 16);
        short8 b0 = *(const short8*)(Bs + (wn * 32 + qr) * 80 + g * 16);
        short8 b1 = *(const short8*)(Bs + (wn * 32 + 16 + qr) * 80 + g * 16);
        acc[0][0] = __builtin_amdgcn_mfma_f32_16x16x32_bf16(a0, b0, acc[0][0], 0, 0, 0);
        acc[0][1] = __builtin_amdgcn_mfma_f32_16x16x32_bf16(a0, b1, acc[0][1], 0, 0, 0);
        acc[1][0] = __builtin_amdgcn_mfma_f32_16x16x32_bf16(a1, b0, acc[1][0], 0, 0, 0);
        acc[1][1] = __builtin_amdgcn_mfma_f32_16x16x32_bf16(a1, b1, acc[1][1], 0, 0, 0);
    }
    #pragma unroll
    for (int mi = 0; mi < 2; ++mi)
        #pragma unroll
        for (int ni = 0; ni < 2; ++ni)
            #pragma unroll
            for (int reg = 0; reg < 4; ++reg) {
                int m = m0 + wm * 32 + 16 * mi + 4 * g + reg;
                int n = n0 + wn * 32 + 16 * ni + qr;
                int bb = m / 100, p = m - bb * 100;
                int nh = n >> 5, d = n & 31;
                q4[(((size_t)bb * NH_ + nh) * P_ + p) * HD_ + d] = acc[mi][ni][reg];
            }
}

// ------------------------------------------------------------------
// combine MFMA: [25600,512] x Wc^T + bias -> mha [25600,512]
// ------------------------------------------------------------------
__global__ __launch_bounds__(256) void combine_mfma(
    const float* __restrict__ ctx, const float* __restrict__ Wc,
    const float* __restrict__ bias, float* __restrict__ mha)
{
    __shared__ char As[64 * 80];
    __shared__ char Bs[64 * 80];
    const int tid = threadIdx.x;
    const int m0 = blockIdx.y * 64, n0 = blockIdx.x * 64;
    const int r = tid >> 2, s = tid & 3;
    const int wave = tid >> 6, lane = tid & 63;
    const int wm = wave >> 1, wn = wave & 1;
    const int g = lane >> 4, qr = lane & 15;

    f32x4 acc[2][2] = {};
    for (int k0 = 0; k0 < 512; k0 += 32) {
        const int k = k0 + 8 * s;
        float4 a = *(const float4*)(ctx + (size_t)(m0 + r) * 512 + k);
        float4 c = *(const float4*)(ctx + (size_t)(m0 + r) * 512 + k + 4);
        uint4 wa, wb;
        wa.x = f2bf(a.x) | (f2bf(a.y) << 16);
        wa.y = f2bf(a.z) | (f2bf(a.w) << 16);
        wa.z = f2bf(c.x) | (f2bf(c.y) << 16);
        wa.w = f2bf(c.z) | (f2bf(c.w) << 16);
        a = *(const float4*)(Wc + (size_t)(n0 + r) * 512 + k);
        c = *(const float4*)(Wc + (size_t)(n0 + r) * 512 + k + 4);
        wb.x = f2bf(a.x) | (f2bf(a.y) << 16);
        wb.y = f2bf(a.z) | (f2bf(a.w) << 16);
        wb.z = f2bf(c.x) | (f2bf(c.y) << 16);
        wb.w = f2bf(c.z) | (f2bf(c.w) << 16);
        __syncthreads();
        *(uint4*)(As + r * 80 + s * 16) = wa;
        *(uint4*)(Bs + r * 80 + s * 16) = wb;
        __syncthreads();
        short8 a0 = *(const short8*)(As + (wm * 32 + qr) * 80 + g * 16);
        short8 a1 = *(const short8*)(As + (wm * 32 + 16 + qr) * 80 + g * 16);
        short8 b0 = *(const short8*)(Bs + (wn * 32 + qr) * 80 + g * 16);
        short8 b1 = *(const short8*)(Bs + (wn * 32 + 16 + qr) * 80 + g * 16);
        acc[0][0] = __builtin_amdgcn_mfma_f32_16x16x32_bf16(a0, b0, acc[0][0], 0, 0, 0);
        acc[0][1] = __builtin_amdgcn_mfma_f32_16x16x32_bf16(a0, b1, acc[0][1], 0, 0, 0);
        acc[1][0] = __builtin_amdgcn_mfma_f32_16x16x32_bf16(a1, b0, acc[1][0], 0, 0, 0);
        acc[1][1] = __builtin_amdgcn_mfma_f32_16x16x32_bf16(a1, b1, acc[1][1], 0, 0, 0);
    }
    const float bia0 = bias[n0 + wn * 32 + qr];
    const float bia1 = bias[n0 + wn * 32 + 16 + qr];
    #pragma unroll
    for (int mi = 0; mi < 2; ++mi)
        #pragma unroll
        for (int ni = 0; ni < 2; ++ni)
            #pragma unroll
            for (int reg = 0; reg < 4; ++reg) {
                int m = m0 + wm * 32 + 16 * mi + 4 * g + reg;
                int n = n0 + wn * 32 + 16 * ni + qr;
                mha[(size_t)m * 512 + n] = acc[mi][ni][reg] + (ni ? bia1 : bia0);
            }
}

// ------------------------------------------------------------------
// logits MFMA: per b, out[p,key] = sum_h mha[b,p,h]*cp[b,h,key]
// ------------------------------------------------------------------
__global__ __launch_bounds__(512) void logits_mfma(
    const float* __restrict__ mha,   // [B*P, 512]
    const float* __restrict__ cp,    // [B, 512, VN]
    float* __restrict__ out)         // [B*P, VN]
{
    __shared__ char As[128 * 80];
    __shared__ char Bs[224 * 80];
    const int b = blockIdx.x;
    const int tid = threadIdx.x;
    const int wave = tid >> 6, lane = tid & 63;
    const int g = lane >> 4, qr = lane & 15;
    const int row = tid >> 2, s = tid & 3;

    f32x4 acc[14] = {};
    for (int h0 = 0; h0 < 512; h0 += 32) {
        uint4 wa = {0,0,0,0};
        if (row < 100) {
            const float* mp = mha + ((size_t)b * P_ + row) * 512 + h0 + 8 * s;
            float4 a = *(const float4*)mp;
            float4 c = *(const float4*)(mp + 4);
            wa.x = f2bf(a.x) | (f2bf(a.y) << 16);
            wa.y = f2bf(a.z) | (f2bf(a.w) << 16);
            wa.z = f2bf(c.x) | (f2bf(c.y) << 16);
            wa.w = f2bf(c.z) | (f2bf(c.w) << 16);
        }
        __syncthreads();
        *(uint4*)(As + row * 80 + s * 16) = wa;
        for (int lin = tid; lin < 224 * 8; lin += 512) {
            int kk = lin % 224, hq = lin / 224;
            int h = hq * 4;
            float v0 = 0.f, v1 = 0.f, v2 = 0.f, v3 = 0.f;
            if (kk < VN_) {
                const float* cpp = cp + ((size_t)b * 512 + h0 + h) * VN_ + kk;
                v0 = cpp[0]; v1 = cpp[VN_]; v2 = cpp[2 * VN_]; v3 = cpp[3 * VN_];
            }
            uint2 w;
            w.x = f2bf(v0) | (f2bf(v1) << 16);
            w.y = f2bf(v2) | (f2bf(v3) << 16);
            *(uint2*)(Bs + kk * 80 + h * 2) = w;
        }
        __syncthreads();
        short8 af = *(const short8*)(As + (wave * 16 + qr) * 80 + g * 16);
        #pragma unroll
        for (int ni = 0; ni < 14; ++ni) {
            short8 bf = *(const short8*)(Bs + (ni * 16 + qr) * 80 + g * 16);
            acc[ni] = __builtin_amdgcn_mfma_f32_16x16x32_bf16(af, bf, acc[ni], 0, 0, 0);
        }
    }
    #pragma unroll
    for (int ni = 0; ni < 14; ++ni) {
        int key = ni * 16 + qr;
        if (key >= VN_) continue;
        #pragma unroll
        for (int reg = 0; reg < 4; ++reg) {
            int p = wave * 16 + 4 * g + reg;
            if (p < P_)
                out[((size_t)b * P_ + p) * VN_ + key] = acc[ni][reg];
        }
    }
}

// ------------------------------------------------------------------
extern "C" void kernel_launch(void* const* d_in, const int* in_sizes, int n_in,
                              void* d_out, int out_size, void* d_ws, size_t ws_size,
                              hipStream_t stream) {
    const float* qg   = (const float*)d_in[0];
    const float* kgl  = (const float*)d_in[1];
    const float* vgl  = (const float*)d_in[2];
    const float* knd  = (const float*)d_in[3];
    const float* vnd  = (const float*)d_in[4];
    const float* kvh  = (const float*)d_in[5];
    const float* vvh  = (const float*)d_in[6];
    const float* kvnd = (const float*)d_in[7];
    const float* vvnd = (const float*)d_in[8];
    const float* cf   = (const float*)d_in[9];
    const float* cp   = (const float*)d_in[10];
    const void*  mask_raw = d_in[11];
    const float* Wq   = (const float*)d_in[12];
    const float* Wc   = (const float*)d_in[13];
    const float* bias = (const float*)d_in[14];
    float* out = (float*)d_out;

    const size_t NQ = (size_t)B_ * NH_ * P_ * HD_;   // 13,107,200 f32
    float* q4buf  = (float*)d_ws;
    float* ctxbuf = q4buf + NQ;
    float* mhabuf = q4buf;                            // reuse: q dead after attn
    unsigned char* mask8 = (unsigned char*)(ctxbuf + NQ);
    const int MASKN_P = B_ * P_ * MASKP;
    int* flag = (int*)(mask8 + ((MASKN_P + 15) & ~15));

    hipFuncSetAttribute(reinterpret_cast<const void*>(attn_mfma_kernel),
                        hipFuncAttributeMaxDynamicSharedMemorySize,
                        ATTN_LDS_B);

    hipMemsetAsync(flag, 0, sizeof(int), stream);
    mask_detect_kernel<<<16, 256, 0, stream>>>(
        (const unsigned int*)mask_raw, 4096, flag);
    mask_repack_kernel<<<(MASKN_P + 255) / 256, 256, 0, stream>>>(
        (const unsigned char*)mask_raw, (const int*)mask_raw, flag, mask8);

    qproj_mfma<<<dim3(8, 400), 256, 0, stream>>>(qg, cf, Wq, q4buf);
    attn_mfma_kernel<<<B_ * NH_, 512, ATTN_LDS_B, stream>>>(
        q4buf, kgl, vgl, knd, vnd, kvh, vvh, kvnd, vvnd, mask8, ctxbuf);
    combine_mfma<<<dim3(8, 400), 256, 0, stream>>>(ctxbuf, Wc, bias, mhabuf);
    logits_mfma<<<B_, 512, 0, stream>>>(mhabuf, cp, out);
}

// Round 12
// 365.818 us; speedup vs baseline: 1.5721x; 1.2205x over previous
//
#include <hip/hip_runtime.h>
#include <hip/hip_bf16.h>

#define B_   256
#define P_   100
#define H_   512
#define NH_  16
#define HD_  32
#define VN_  221
#define KNODE 201
#define KVEH  21
#define KVND  20
#define CSD_ 16
#define MASKP 224                       // padded mask row stride (aligned dwords)

typedef __attribute__((ext_vector_type(8))) short short8;
typedef __attribute__((ext_vector_type(4))) float f32x4;

// ---- attention LDS layout (bytes) ----
// K   : 480 rows x 80B  (32 bf16 + 16B pad; 16B-stride 5 odd -> benign)   [0, 38400)
// V^T : 32 rows  x 976B (480 keys bf16; 16B-stride 61 odd)                [38400, 69632)
#define K_OFF   0
#define V_OFF   38400
#define ATTN_LDS_B 69632

__device__ __forceinline__ unsigned cvtpk(float lo, float hi) {
    unsigned r;
    asm("v_cvt_pk_bf16_f32 %0, %1, %2" : "=v"(r) : "v"(lo), "v"(hi));
    return r;
}
__device__ __forceinline__ unsigned f2bf(float f) {
    union { float f; unsigned u; } x; x.f = f;
    return (x.u + 0x7FFFu + ((x.u >> 16) & 1u)) >> 16;   // RNE bf16 bits
}

// ------------------------------------------------------------------
// mask dtype probe + repack to padded [B*P][224] u8 (pad = 1 = illegal)
// ------------------------------------------------------------------
__global__ void mask_detect_kernel(const unsigned int* __restrict__ w,
                                   int nwords, int* __restrict__ flag) {
    int i = blockIdx.x * 256 + threadIdx.x;
    if (i < nwords && (w[i] & ~1u)) atomicOr(flag, 1);
}

__global__ void mask_repack_kernel(const unsigned char* __restrict__ mb,
                                   const int* __restrict__ mw,
                                   const int* __restrict__ flag,
                                   unsigned char* __restrict__ out) {
    int i = blockIdx.x * blockDim.x + threadIdx.x;
    if (i >= B_ * P_ * MASKP) return;
    int row = i / MASKP, k = i - row * MASKP;
    unsigned char v = 1;
    if (k < VN_) {
        int src = row * VN_ + k;
        v = (*flag) ? (unsigned char)(mb[src] != 0) : (unsigned char)(mw[src] != 0);
    }
    out[i] = v;
}

// ------------------------------------------------------------------
// one source: QK MFMA, exp2, bpermute-gather P, PV MFMA.  (r11 compute)
// ------------------------------------------------------------------
template<bool MASKED, int C0, int C1, int LO, int HI>
__device__ __forceinline__ void attend_v5(
    const char* __restrict__ ldsb,
    const unsigned* __restrict__ mpre,
    short8 qf, int g, int qr, int addrA, int addrB,
    f32x4& O0, f32x4& O1)
{
    f32x4 A0a = {0.f,0.f,0.f,0.f}, A1a = {0.f,0.f,0.f,0.f};
    f32x4 A0b = {0.f,0.f,0.f,0.f}, A1b = {0.f,0.f,0.f,0.f};
    float ssum = 0.f;
    const bool sel = g < 2;
    #pragma unroll
    for (int c = C0; c <= C1; ++c) {
        const int kb = c * 32;
        short8 kf0 = *(const short8*)(ldsb + K_OFF + (size_t)(kb + qr) * 80 + g * 16);
        short8 kf1 = *(const short8*)(ldsb + K_OFF + (size_t)(kb + 16 + qr) * 80 + g * 16);
        __builtin_amdgcn_s_setprio(1);
        f32x4 s0 = __builtin_amdgcn_mfma_f32_16x16x32_bf16(
                       kf0, qf, (f32x4){0.f,0.f,0.f,0.f}, 0, 0, 0);
        f32x4 s1 = __builtin_amdgcn_mfma_f32_16x16x32_bf16(
                       kf1, qf, (f32x4){0.f,0.f,0.f,0.f}, 0, 0, 0);
        __builtin_amdgcn_s_setprio(0);
        unsigned mdw0 = 0, mdw1 = 0;
        if (MASKED) {
            mdw0 = mpre[2 * (c - C0)];
            mdw1 = mpre[2 * (c - C0) + 1];
        }
        float e0[4], e1[4];
        #pragma unroll
        for (int r = 0; r < 4; ++r) {
            const int key0 = kb + 4 * g + r;
            const int key1 = key0 + 16;
            float x0 = exp2f(s0[r]);             // log2e folded into qf scale
            float x1 = exp2f(s1[r]);
            bool ok0, ok1;
            if (MASKED) {
                ok0 = ((mdw0 >> (8 * r)) & 255u) == 0u;
                ok1 = ((mdw1 >> (8 * r)) & 255u) == 0u;
            } else {
                ok0 = (key0 >= LO) & (key0 < HI);
                ok1 = (key1 >= LO) & (key1 < HI);
            }
            e0[r] = ok0 ? x0 : 0.f;
            e1[r] = ok1 ? x1 : 0.f;
            ssum += e0[r] + e1[r];
        }
        unsigned w0 = cvtpk(e0[0], e0[1]), w1 = cvtpk(e0[2], e0[3]);
        unsigned w2 = cvtpk(e1[0], e1[1]), w3 = cvtpk(e1[2], e1[3]);
        int pA0 = __builtin_amdgcn_ds_bpermute(addrA, (int)w0);
        int pA1 = __builtin_amdgcn_ds_bpermute(addrA, (int)w1);
        int pB0 = __builtin_amdgcn_ds_bpermute(addrB, (int)w0);
        int pB1 = __builtin_amdgcn_ds_bpermute(addrB, (int)w1);
        int qA0 = __builtin_amdgcn_ds_bpermute(addrA, (int)w2);
        int qA1 = __builtin_amdgcn_ds_bpermute(addrA, (int)w3);
        int qB0 = __builtin_amdgcn_ds_bpermute(addrB, (int)w2);
        int qB1 = __builtin_amdgcn_ds_bpermute(addrB, (int)w3);
        union { int u[4]; short8 s8; } pf;
        pf.u[0] = sel ? pA0 : qA0;
        pf.u[1] = sel ? pA1 : qA1;
        pf.u[2] = sel ? pB0 : qB0;
        pf.u[3] = sel ? pB1 : qB1;
        short8 v0 = *(const short8*)(ldsb + V_OFF + (size_t)qr * 976 + kb * 2 + g * 16);
        short8 v1 = *(const short8*)(ldsb + V_OFF + (size_t)(qr + 16) * 976 + kb * 2 + g * 16);
        __builtin_amdgcn_s_setprio(1);
        if (c & 1) {
            A0b = __builtin_amdgcn_mfma_f32_16x16x32_bf16(v0, pf.s8, A0b, 0, 0, 0);
            A1b = __builtin_amdgcn_mfma_f32_16x16x32_bf16(v1, pf.s8, A1b, 0, 0, 0);
        } else {
            A0a = __builtin_amdgcn_mfma_f32_16x16x32_bf16(v0, pf.s8, A0a, 0, 0, 0);
            A1a = __builtin_amdgcn_mfma_f32_16x16x32_bf16(v1, pf.s8, A1a, 0, 0, 0);
        }
        __builtin_amdgcn_s_setprio(0);
    }
    ssum += __shfl_xor(ssum, 16);
    ssum += __shfl_xor(ssum, 32);
    const float inv = 1.f / ssum;
    O0 += (A0a + A0b) * inv;
    O1 += (A1a + A1b) * inv;
}

// ------------------------------------------------------------------
// MFMA attention: one block per (b,nh); 512 threads; K/V^T bf16 in LDS.
// Staging rewritten for memory-level parallelism: flattened slot space,
// 4x unrolled two-phase (batch loads -> convert+write), vectorized V reads.
// ------------------------------------------------------------------
__global__ __launch_bounds__(512, 4) void attn_mfma_kernel(
    const float* __restrict__ q4,
    const float* __restrict__ kg,  const float* __restrict__ vg,
    const float* __restrict__ kn,  const float* __restrict__ vn,
    const float* __restrict__ kv,  const float* __restrict__ vv,
    const float* __restrict__ kvn, const float* __restrict__ vvn,
    const unsigned char* __restrict__ maskp,
    float* __restrict__ ctx_out)
{
    extern __shared__ char ldsb[];
    const int tid = threadIdx.x;
    const int bh = blockIdx.x, b = bh >> 4, nh = bh & 15;

    // ---- early per-wave state + prefetch (latency hides under staging) ----
    const int wave = tid >> 6;
    const int g = (tid >> 4) & 3, qr = tid & 15;
    const int q0 = wave * 16;
    const int qe = (q0 + qr < 100) ? (q0 + qr) : 99;   // valid addr for all waves
    const float* qp = q4 + ((size_t)bh * 100 + qe) * 32 + g * 8;
    float4 qa = *(const float4*)qp;
    float4 qc = *(const float4*)(qp + 4);
    const unsigned char* mrow = maskp + ((size_t)b * 100 + qe) * MASKP;
    unsigned mpre[14];
    #pragma unroll
    for (int c = 0; c < 7; ++c) {
        mpre[2 * c]     = *(const unsigned*)(mrow + c * 32 + g * 4);
        mpre[2 * c + 1] = *(const unsigned*)(mrow + c * 32 + 16 + g * 4);
    }

    // per-bh source bases
    const float* kg_s  = kg  + (size_t)bh * VN_   * 32;
    const float* kn_s  = kn  + (size_t)bh * KNODE * 32;
    const float* kv_s  = kv  + (size_t)bh * KVEH  * 32;
    const float* kvn_s = kvn + (size_t)bh * KVND  * 32;
    const float* vg_s  = vg  + (size_t)bh * VN_   * 32;
    const float* vn_s  = vn  + (size_t)bh * KNODE * 32;
    const float* vv_s  = vv  + (size_t)bh * KVEH  * 32;
    const float* vvn_s = vvn + (size_t)bh * KVND  * 32;

    // ==== K staging: flattened slots 0..1851 (= key*4quads over 4 srcs) ====
    // boundaries: 221*4=884 | +201*4=1688 | +21*4=1772 | +20*4=1852
    {
        float4 ka[4], kc[4];
        int koff[4]; bool kok[4];
        #pragma unroll
        for (int it = 0; it < 4; ++it) {
            int slot = tid + it * 512;
            kok[it] = slot < 1852;
            const float* sp; int li, r0;
            if (slot >= 1772)      { sp = kvn_s; li = slot - 1772; r0 = 456; }
            else if (slot >= 1688) { sp = kv_s;  li = slot - 1688; r0 = 432; }
            else if (slot >= 884)  { sp = kn_s;  li = slot - 884;  r0 = 224; }
            else                   { sp = kg_s;  li = slot;        r0 = 0;   }
            int r = li >> 2, s2 = li & 3;
            koff[it] = (r0 + r) * 80 + s2 * 16;
            if (kok[it]) {
                ka[it] = *(const float4*)(sp + r * 32 + s2 * 8);
                kc[it] = *(const float4*)(sp + r * 32 + s2 * 8 + 4);
            }
        }
        #pragma unroll
        for (int it = 0; it < 4; ++it) {
            if (kok[it]) {
                uint4 w;
                w.x = cvtpk(ka[it].x, ka[it].y); w.y = cvtpk(ka[it].z, ka[it].w);
                w.z = cvtpk(kc[it].x, kc[it].y); w.w = cvtpk(kc[it].z, kc[it].w);
                *(uint4*)(ldsb + K_OFF + koff[it]) = w;
            }
        }
    }
    // K zero-pad rows (221-223, 425-431, 453-455, 476-479)
    for (int lin = tid; lin < 17 * 4; lin += 512) {
        int zi = lin >> 2, s = lin & 3;
        int zr = (zi < 3) ? 221 + zi : (zi < 10) ? 422 + zi
               : (zi < 13) ? 443 + zi : 463 + zi;
        *(uint4*)(ldsb + K_OFF + (size_t)zr * 80 + s * 16) = (uint4){0,0,0,0};
    }

    // ==== V^T staging: flattened pair-quad slots 0..1839 ====
    // slot = (keypair p, dimquad dq): sizes 110*8=880 | +100*8=1680 | +10*8=1760 | +10*8=1840
    {
        char* vb = ldsb + V_OFF;
        float4 va[4], vb4[4];
        int vd0[4], vk2[4]; bool vok[4];
        #pragma unroll
        for (int it = 0; it < 4; ++it) {
            int slot = tid + it * 512;
            vok[it] = slot < 1840;
            const float* sp; int li, r0;
            if (slot >= 1760)      { sp = vvn_s; li = slot - 1760; r0 = 456; }
            else if (slot >= 1680) { sp = vv_s;  li = slot - 1680; r0 = 432; }
            else if (slot >= 880)  { sp = vn_s;  li = slot - 880;  r0 = 224; }
            else                   { sp = vg_s;  li = slot;        r0 = 0;   }
            int p = li >> 3, dq = li & 7;
            vd0[it] = dq * 4;
            vk2[it] = (r0 + 2 * p) * 2;
            if (vok[it]) {
                va[it]  = *(const float4*)(sp + (2 * p) * 32 + dq * 4);
                vb4[it] = *(const float4*)(sp + (2 * p + 1) * 32 + dq * 4);
            }
        }
        #pragma unroll
        for (int it = 0; it < 4; ++it) {
            if (vok[it]) {
                int d0 = vd0[it], k2 = vk2[it];
                *(unsigned*)(vb + (size_t)(d0 + 0) * 976 + k2) = cvtpk(va[it].x, vb4[it].x);
                *(unsigned*)(vb + (size_t)(d0 + 1) * 976 + k2) = cvtpk(va[it].y, vb4[it].y);
                *(unsigned*)(vb + (size_t)(d0 + 2) * 976 + k2) = cvtpk(va[it].z, vb4[it].z);
                *(unsigned*)(vb + (size_t)(d0 + 3) * 976 + k2) = cvtpk(va[it].w, vb4[it].w);
            }
        }
        // odd-row tails: abs keys 220 (src0), 424 (src1), 452 (src2); hi half = 0
        if (tid < 32) {
            int d = tid;
            *(unsigned*)(vb + (size_t)d * 976 + 220 * 2) = cvtpk(vg_s[220 * 32 + d], 0.f);
            *(unsigned*)(vb + (size_t)d * 976 + 424 * 2) = cvtpk(vn_s[200 * 32 + d], 0.f);
            *(unsigned*)(vb + (size_t)d * 976 + 452 * 2) = cvtpk(vv_s[20 * 32 + d], 0.f);
        }
        // zero pad pairs: 222, 426, 428, 430, 454, 476, 478
        for (int lin = tid; lin < 7 * 32; lin += 512) {
            int pi = lin >> 5, d = lin & 31;
            int pk = (pi == 0) ? 222 : (pi < 4) ? 424 + 2 * pi
                   : (pi == 4) ? 454 : 466 + 2 * pi;
            *(unsigned*)(vb + (size_t)d * 976 + (size_t)pk * 2) = 0;
        }
    }
    __syncthreads();

    if (wave >= 7) return;                 // 7 q-tiles of 16 cover P=100

    // Q frag, scale*log2(e) folded in (exp2 downstream)
    short8 qf;
    {
        const float SC = 0.2550524218f;    // 32^-.5 * log2(e)
        union { unsigned u[4]; short8 s8; } q;
        q.u[0] = cvtpk(qa.x * SC, qa.y * SC);
        q.u[1] = cvtpk(qa.z * SC, qa.w * SC);
        q.u[2] = cvtpk(qc.x * SC, qc.y * SC);
        q.u[3] = cvtpk(qc.z * SC, qc.w * SC);
        qf = q.s8;
    }
    const int addrA = 4 * (qr + ((g & 1) << 5));
    const int addrB = addrA + 64;

    f32x4 O0 = {0.f,0.f,0.f,0.f}, O1 = {0.f,0.f,0.f,0.f};
    attend_v5<true,  0,  6,   0, 224>(ldsb, mpre, qf, g, qr, addrA, addrB, O0, O1);
    attend_v5<false, 7, 13, 224, 425>(ldsb, nullptr, qf, g, qr, addrA, addrB, O0, O1);
    attend_v5<false,13, 14, 432, 453>(ldsb, nullptr, qf, g, qr, addrA, addrB, O0, O1);
    attend_v5<false,14, 14, 456, 476>(ldsb, nullptr, qf, g, qr, addrA, addrB, O0, O1);

    if (q0 + qr < 100) {
        float* op = ctx_out + ((size_t)b * 100 + q0 + qr) * 512 + nh * 32 + 4 * g;
        *(f32x4*)op        = O0;
        *(f32x4*)(op + 16) = O1;
    }
}

// ------------------------------------------------------------------
// qproj MFMA: [25600,544pad] x Wq^T -> q4 [B,NH,P,HD]
// ------------------------------------------------------------------
__global__ __launch_bounds__(256) void qproj_mfma(
    const float* __restrict__ qg, const float* __restrict__ cf,
    const float* __restrict__ Wq, float* __restrict__ q4)
{
    __shared__ char As[64 * 80];
    __shared__ char Bs[64 * 80];
    const int tid = threadIdx.x;
    const int m0 = blockIdx.y * 64, n0 = blockIdx.x * 64;
    const int r = tid >> 2, s = tid & 3;
    const int wave = tid >> 6, lane = tid & 63;
    const int wm = wave >> 1, wn = wave & 1;
    const int g = lane >> 4, qr = lane & 15;

    f32x4 acc[2][2] = {};
    for (int k0 = 0; k0 < 544; k0 += 32) {
        const int k = k0 + 8 * s;
        uint4 wa = {0,0,0,0}, wb = {0,0,0,0};
        {
            float4 a = {0,0,0,0}, c = {0,0,0,0};
            const int row = m0 + r;
            if (k < 512) {
                a = *(const float4*)(qg + (size_t)row * 512 + k);
                c = *(const float4*)(qg + (size_t)row * 512 + k + 4);
            } else if (k < 528) {
                a = *(const float4*)(cf + (size_t)row * 16 + (k - 512));
                c = *(const float4*)(cf + (size_t)row * 16 + (k - 512) + 4);
            }
            wa.x = f2bf(a.x) | (f2bf(a.y) << 16);
            wa.y = f2bf(a.z) | (f2bf(a.w) << 16);
            wa.z = f2bf(c.x) | (f2bf(c.y) << 16);
            wa.w = f2bf(c.z) | (f2bf(c.w) << 16);
        }
        {
            float4 a = {0,0,0,0}, c = {0,0,0,0};
            const int row = n0 + r;
            if (k < 528) {
                a = *(const float4*)(Wq + (size_t)row * 528 + k);
                c = *(const float4*)(Wq + (size_t)row * 528 + k + 4);
            }
            wb.x = f2bf(a.x) | (f2bf(a.y) << 16);
            wb.y = f2bf(a.z) | (f2bf(a.w) << 16);
            wb.z = f2bf(c.x) | (f2bf(c.y) << 16);
            wb.w = f2bf(c.z) | (f2bf(c.w) << 16);
        }
        __syncthreads();
        *(uint4*)(As + r * 80 + s * 16) = wa;
        *(uint4*)(Bs + r * 80 + s * 16) = wb;
        __syncthreads();
        short8 a0 = *(const short8*)(As + (wm * 32 + qr) * 80 + g * 16);
        short8 a1 = *(const short8*)(As + (wm * 32 + 16 + qr) * 80 + g * 16);
        short8 b0 = *(const short8*)(Bs + (wn * 32 + qr) * 80 + g * 16);
        short8 b1 = *(const short8*)(Bs + (wn * 32 + 16 + qr) * 80 + g * 16);
        acc[0][0] = __builtin_amdgcn_mfma_f32_16x16x32_bf16(a0, b0, acc[0][0], 0, 0, 0);
        acc[0][1] = __builtin_amdgcn_mfma_f32_16x16x32_bf16(a0, b1, acc[0][1], 0, 0, 0);
        acc[1][0] = __builtin_amdgcn_mfma_f32_16x16x32_bf16(a1, b0, acc[1][0], 0, 0, 0);
        acc[1][1] = __builtin_amdgcn_mfma_f32_16x16x32_bf16(a1, b1, acc[1][1], 0, 0, 0);
    }
    #pragma unroll
    for (int mi = 0; mi < 2; ++mi)
        #pragma unroll
        for (int ni = 0; ni < 2; ++ni)
            #pragma unroll
            for (int reg = 0; reg < 4; ++reg) {
                int m = m0 + wm * 32 + 16 * mi + 4 * g + reg;
                int n = n0 + wn * 32 + 16 * ni + qr;
                int bb = m / 100, p = m - bb * 100;
                int nh = n >> 5, d = n & 31;
                q4[(((size_t)bb * NH_ + nh) * P_ + p) * HD_ + d] = acc[mi][ni][reg];
            }
}

// ------------------------------------------------------------------
// combine MFMA: [25600,512] x Wc^T + bias -> mha [25600,512]
// ------------------------------------------------------------------
__global__ __launch_bounds__(256) void combine_mfma(
    const float* __restrict__ ctx, const float* __restrict__ Wc,
    const float* __restrict__ bias, float* __restrict__ mha)
{
    __shared__ char As[64 * 80];
    __shared__ char Bs[64 * 80];
    const int tid = threadIdx.x;
    const int m0 = blockIdx.y * 64, n0 = blockIdx.x * 64;
    const int r = tid >> 2, s = tid & 3;
    const int wave = tid >> 6, lane = tid & 63;
    const int wm = wave >> 1, wn = wave & 1;
    const int g = lane >> 4, qr = lane & 15;

    f32x4 acc[2][2] = {};
    for (int k0 = 0; k0 < 512; k0 += 32) {
        const int k = k0 + 8 * s;
        float4 a = *(const float4*)(ctx + (size_t)(m0 + r) * 512 + k);
        float4 c = *(const float4*)(ctx + (size_t)(m0 + r) * 512 + k + 4);
        uint4 wa, wb;
        wa.x = f2bf(a.x) | (f2bf(a.y) << 16);
        wa.y = f2bf(a.z) | (f2bf(a.w) << 16);
        wa.z = f2bf(c.x) | (f2bf(c.y) << 16);
        wa.w = f2bf(c.z) | (f2bf(c.w) << 16);
        a = *(const float4*)(Wc + (size_t)(n0 + r) * 512 + k);
        c = *(const float4*)(Wc + (size_t)(n0 + r) * 512 + k + 4);
        wb.x = f2bf(a.x) | (f2bf(a.y) << 16);
        wb.y = f2bf(a.z) | (f2bf(a.w) << 16);
        wb.z = f2bf(c.x) | (f2bf(c.y) << 16);
        wb.w = f2bf(c.z) | (f2bf(c.w) << 16);
        __syncthreads();
        *(uint4*)(As + r * 80 + s * 16) = wa;
        *(uint4*)(Bs + r * 80 + s * 16) = wb;
        __syncthreads();
        short8 a0 = *(const short8*)(As + (wm * 32 + qr) * 80 + g * 16);
        short8 a1 = *(const short8*)(As + (wm * 32 + 16 + qr) * 80 + g * 16);
        short8 b0 = *(const short8*)(Bs + (wn * 32 + qr) * 80 + g * 16);
        short8 b1 = *(const short8*)(Bs + (wn * 32 + 16 + qr) * 80 + g * 16);
        acc[0][0] = __builtin_amdgcn_mfma_f32_16x16x32_bf16(a0, b0, acc[0][0], 0, 0, 0);
        acc[0][1] = __builtin_amdgcn_mfma_f32_16x16x32_bf16(a0, b1, acc[0][1], 0, 0, 0);
        acc[1][0] = __builtin_amdgcn_mfma_f32_16x16x32_bf16(a1, b0, acc[1][0], 0, 0, 0);
        acc[1][1] = __builtin_amdgcn_mfma_f32_16x16x32_bf16(a1, b1, acc[1][1], 0, 0, 0);
    }
    const float bia0 = bias[n0 + wn * 32 + qr];
    const float bia1 = bias[n0 + wn * 32 + 16 + qr];
    #pragma unroll
    for (int mi = 0; mi < 2; ++mi)
        #pragma unroll
        for (int ni = 0; ni < 2; ++ni)
            #pragma unroll
            for (int reg = 0; reg < 4; ++reg) {
                int m = m0 + wm * 32 + 16 * mi + 4 * g + reg;
                int n = n0 + wn * 32 + 16 * ni + qr;
                mha[(size_t)m * 512 + n] = acc[mi][ni][reg] + (ni ? bia1 : bia0);
            }
}

// ------------------------------------------------------------------
// logits MFMA: per b, out[p,key] = sum_h mha[b,p,h]*cp[b,h,key]
// ------------------------------------------------------------------
__global__ __launch_bounds__(512) void logits_mfma(
    const float* __restrict__ mha,   // [B*P, 512]
    const float* __restrict__ cp,    // [B, 512, VN]
    float* __restrict__ out)         // [B*P, VN]
{
    __shared__ char As[128 * 80];
    __shared__ char Bs[224 * 80];
    const int b = blockIdx.x;
    const int tid = threadIdx.x;
    const int wave = tid >> 6, lane = tid & 63;
    const int g = lane >> 4, qr = lane & 15;
    const int row = tid >> 2, s = tid & 3;

    f32x4 acc[14] = {};
    for (int h0 = 0; h0 < 512; h0 += 32) {
        uint4 wa = {0,0,0,0};
        if (row < 100) {
            const float* mp = mha + ((size_t)b * P_ + row) * 512 + h0 + 8 * s;
            float4 a = *(const float4*)mp;
            float4 c = *(const float4*)(mp + 4);
            wa.x = f2bf(a.x) | (f2bf(a.y) << 16);
            wa.y = f2bf(a.z) | (f2bf(a.w) << 16);
            wa.z = f2bf(c.x) | (f2bf(c.y) << 16);
            wa.w = f2bf(c.z) | (f2bf(c.w) << 16);
        }
        __syncthreads();
        *(uint4*)(As + row * 80 + s * 16) = wa;
        for (int lin = tid; lin < 224 * 8; lin += 512) {
            int kk = lin % 224, hq = lin / 224;
            int h = hq * 4;
            float v0 = 0.f, v1 = 0.f, v2 = 0.f, v3 = 0.f;
            if (kk < VN_) {
                const float* cpp = cp + ((size_t)b * 512 + h0 + h) * VN_ + kk;
                v0 = cpp[0]; v1 = cpp[VN_]; v2 = cpp[2 * VN_]; v3 = cpp[3 * VN_];
            }
            uint2 w;
            w.x = f2bf(v0) | (f2bf(v1) << 16);
            w.y = f2bf(v2) | (f2bf(v3) << 16);
            *(uint2*)(Bs + kk * 80 + h * 2) = w;
        }
        __syncthreads();
        short8 af = *(const short8*)(As + (wave * 16 + qr) * 80 + g * 16);
        #pragma unroll
        for (int ni = 0; ni < 14; ++ni) {
            short8 bf = *(const short8*)(Bs + (ni * 16 + qr) * 80 + g * 16);
            acc[ni] = __builtin_amdgcn_mfma_f32_16x16x32_bf16(af, bf, acc[ni], 0, 0, 0);
        }
    }
    #pragma unroll
    for (int ni = 0; ni < 14; ++ni) {
        int key = ni * 16 + qr;
        if (key >= VN_) continue;
        #pragma unroll
        for (int reg = 0; reg < 4; ++reg) {
            int p = wave * 16 + 4 * g + reg;
            if (p < P_)
                out[((size_t)b * P_ + p) * VN_ + key] = acc[ni][reg];
        }
    }
}

// ------------------------------------------------------------------
extern "C" void kernel_launch(void* const* d_in, const int* in_sizes, int n_in,
                              void* d_out, int out_size, void* d_ws, size_t ws_size,
                              hipStream_t stream) {
    const float* qg   = (const float*)d_in[0];
    const float* kgl  = (const float*)d_in[1];
    const float* vgl  = (const float*)d_in[2];
    const float* knd  = (const float*)d_in[3];
    const float* vnd  = (const float*)d_in[4];
    const float* kvh  = (const float*)d_in[5];
    const float* vvh  = (const float*)d_in[6];
    const float* kvnd = (const float*)d_in[7];
    const float* vvnd = (const float*)d_in[8];
    const float* cf   = (const float*)d_in[9];
    const float* cp   = (const float*)d_in[10];
    const void*  mask_raw = d_in[11];
    const float* Wq   = (const float*)d_in[12];
    const float* Wc   = (const float*)d_in[13];
    const float* bias = (const float*)d_in[14];
    float* out = (float*)d_out;

    const size_t NQ = (size_t)B_ * NH_ * P_ * HD_;   // 13,107,200 f32
    float* q4buf  = (float*)d_ws;
    float* ctxbuf = q4buf + NQ;
    float* mhabuf = q4buf;                            // reuse: q dead after attn
    unsigned char* mask8 = (unsigned char*)(ctxbuf + NQ);
    const int MASKN_P = B_ * P_ * MASKP;
    int* flag = (int*)(mask8 + ((MASKN_P + 15) & ~15));

    hipFuncSetAttribute(reinterpret_cast<const void*>(attn_mfma_kernel),
                        hipFuncAttributeMaxDynamicSharedMemorySize,
                        ATTN_LDS_B);

    hipMemsetAsync(flag, 0, sizeof(int), stream);
    mask_detect_kernel<<<16, 256, 0, stream>>>(
        (const unsigned int*)mask_raw, 4096, flag);
    mask_repack_kernel<<<(MASKN_P + 255) / 256, 256, 0, stream>>>(
        (const unsigned char*)mask_raw, (const int*)mask_raw, flag, mask8);

    qproj_mfma<<<dim3(8, 400), 256, 0, stream>>>(qg, cf, Wq, q4buf);
    attn_mfma_kernel<<<B_ * NH_, 512, ATTN_LDS_B, stream>>>(
        q4buf, kgl, vgl, knd, vnd, kvh, vvh, kvnd, vvnd, mask8, ctxbuf);
    combine_mfma<<<dim3(8, 400), 256, 0, stream>>>(ctxbuf, Wc, bias, mhabuf);
    logits_mfma<<<B_, 512, 0, stream>>>(mhabuf, cp, out);
}

// Round 13
// 361.649 us; speedup vs baseline: 1.5902x; 1.0115x over previous
//
#include <hip/hip_runtime.h>
#include <hip/hip_bf16.h>

#define B_   256
#define P_   100
#define H_   512
#define NH_  16
#define HD_  32
#define VN_  221
#define KNODE 201
#define KVEH  21
#define KVND  20
#define CSD_ 16
#define MASKP 224                       // padded mask row stride (aligned dwords)

typedef __attribute__((ext_vector_type(8))) short short8;
typedef __attribute__((ext_vector_type(4))) float f32x4;

// ---- attention LDS layout (bytes) ----
#define K_OFF   0
#define V_OFF   38400
#define ATTN_LDS_B 69632

__device__ __forceinline__ unsigned cvtpk(float lo, float hi) {
    unsigned r;
    asm("v_cvt_pk_bf16_f32 %0, %1, %2" : "=v"(r) : "v"(lo), "v"(hi));
    return r;
}
__device__ __forceinline__ unsigned f2bf(float f) {
    union { float f; unsigned u; } x; x.f = f;
    return (x.u + 0x7FFFu + ((x.u >> 16) & 1u)) >> 16;   // RNE bf16 bits
}

// ------------------------------------------------------------------
// mask dtype probe + repack to padded [B*P][224] u8 (pad = 1 = illegal)
// ------------------------------------------------------------------
__global__ void mask_detect_kernel(const unsigned int* __restrict__ w,
                                   int nwords, int* __restrict__ flag) {
    int i = blockIdx.x * 256 + threadIdx.x;
    if (i < nwords && (w[i] & ~1u)) atomicOr(flag, 1);
}

__global__ void mask_repack_kernel(const unsigned char* __restrict__ mb,
                                   const int* __restrict__ mw,
                                   const int* __restrict__ flag,
                                   unsigned char* __restrict__ out) {
    int i = blockIdx.x * blockDim.x + threadIdx.x;
    if (i >= B_ * P_ * MASKP) return;
    int row = i / MASKP, k = i - row * MASKP;
    unsigned char v = 1;
    if (k < VN_) {
        int src = row * VN_ + k;
        v = (*flag) ? (unsigned char)(mb[src] != 0) : (unsigned char)(mw[src] != 0);
    }
    out[i] = v;
}

// ------------------------------------------------------------------
// attention (r12 — unchanged)
// ------------------------------------------------------------------
template<bool MASKED, int C0, int C1, int LO, int HI>
__device__ __forceinline__ void attend_v5(
    const char* __restrict__ ldsb,
    const unsigned* __restrict__ mpre,
    short8 qf, int g, int qr, int addrA, int addrB,
    f32x4& O0, f32x4& O1)
{
    f32x4 A0a = {0.f,0.f,0.f,0.f}, A1a = {0.f,0.f,0.f,0.f};
    f32x4 A0b = {0.f,0.f,0.f,0.f}, A1b = {0.f,0.f,0.f,0.f};
    float ssum = 0.f;
    const bool sel = g < 2;
    #pragma unroll
    for (int c = C0; c <= C1; ++c) {
        const int kb = c * 32;
        short8 kf0 = *(const short8*)(ldsb + K_OFF + (size_t)(kb + qr) * 80 + g * 16);
        short8 kf1 = *(const short8*)(ldsb + K_OFF + (size_t)(kb + 16 + qr) * 80 + g * 16);
        __builtin_amdgcn_s_setprio(1);
        f32x4 s0 = __builtin_amdgcn_mfma_f32_16x16x32_bf16(
                       kf0, qf, (f32x4){0.f,0.f,0.f,0.f}, 0, 0, 0);
        f32x4 s1 = __builtin_amdgcn_mfma_f32_16x16x32_bf16(
                       kf1, qf, (f32x4){0.f,0.f,0.f,0.f}, 0, 0, 0);
        __builtin_amdgcn_s_setprio(0);
        unsigned mdw0 = 0, mdw1 = 0;
        if (MASKED) {
            mdw0 = mpre[2 * (c - C0)];
            mdw1 = mpre[2 * (c - C0) + 1];
        }
        float e0[4], e1[4];
        #pragma unroll
        for (int r = 0; r < 4; ++r) {
            const int key0 = kb + 4 * g + r;
            const int key1 = key0 + 16;
            float x0 = exp2f(s0[r]);             // log2e folded into qf scale
            float x1 = exp2f(s1[r]);
            bool ok0, ok1;
            if (MASKED) {
                ok0 = ((mdw0 >> (8 * r)) & 255u) == 0u;
                ok1 = ((mdw1 >> (8 * r)) & 255u) == 0u;
            } else {
                ok0 = (key0 >= LO) & (key0 < HI);
                ok1 = (key1 >= LO) & (key1 < HI);
            }
            e0[r] = ok0 ? x0 : 0.f;
            e1[r] = ok1 ? x1 : 0.f;
            ssum += e0[r] + e1[r];
        }
        unsigned w0 = cvtpk(e0[0], e0[1]), w1 = cvtpk(e0[2], e0[3]);
        unsigned w2 = cvtpk(e1[0], e1[1]), w3 = cvtpk(e1[2], e1[3]);
        int pA0 = __builtin_amdgcn_ds_bpermute(addrA, (int)w0);
        int pA1 = __builtin_amdgcn_ds_bpermute(addrA, (int)w1);
        int pB0 = __builtin_amdgcn_ds_bpermute(addrB, (int)w0);
        int pB1 = __builtin_amdgcn_ds_bpermute(addrB, (int)w1);
        int qA0 = __builtin_amdgcn_ds_bpermute(addrA, (int)w2);
        int qA1 = __builtin_amdgcn_ds_bpermute(addrA, (int)w3);
        int qB0 = __builtin_amdgcn_ds_bpermute(addrB, (int)w2);
        int qB1 = __builtin_amdgcn_ds_bpermute(addrB, (int)w3);
        union { int u[4]; short8 s8; } pf;
        pf.u[0] = sel ? pA0 : qA0;
        pf.u[1] = sel ? pA1 : qA1;
        pf.u[2] = sel ? pB0 : qB0;
        pf.u[3] = sel ? pB1 : qB1;
        short8 v0 = *(const short8*)(ldsb + V_OFF + (size_t)qr * 976 + kb * 2 + g * 16);
        short8 v1 = *(const short8*)(ldsb + V_OFF + (size_t)(qr + 16) * 976 + kb * 2 + g * 16);
        __builtin_amdgcn_s_setprio(1);
        if (c & 1) {
            A0b = __builtin_amdgcn_mfma_f32_16x16x32_bf16(v0, pf.s8, A0b, 0, 0, 0);
            A1b = __builtin_amdgcn_mfma_f32_16x16x32_bf16(v1, pf.s8, A1b, 0, 0, 0);
        } else {
            A0a = __builtin_amdgcn_mfma_f32_16x16x32_bf16(v0, pf.s8, A0a, 0, 0, 0);
            A1a = __builtin_amdgcn_mfma_f32_16x16x32_bf16(v1, pf.s8, A1a, 0, 0, 0);
        }
        __builtin_amdgcn_s_setprio(0);
    }
    ssum += __shfl_xor(ssum, 16);
    ssum += __shfl_xor(ssum, 32);
    const float inv = 1.f / ssum;
    O0 += (A0a + A0b) * inv;
    O1 += (A1a + A1b) * inv;
}

__global__ __launch_bounds__(512, 4) void attn_mfma_kernel(
    const float* __restrict__ q4,
    const float* __restrict__ kg,  const float* __restrict__ vg,
    const float* __restrict__ kn,  const float* __restrict__ vn,
    const float* __restrict__ kv,  const float* __restrict__ vv,
    const float* __restrict__ kvn, const float* __restrict__ vvn,
    const unsigned char* __restrict__ maskp,
    float* __restrict__ ctx_out)
{
    extern __shared__ char ldsb[];
    const int tid = threadIdx.x;
    const int bh = blockIdx.x, b = bh >> 4, nh = bh & 15;

    const int wave = tid >> 6;
    const int g = (tid >> 4) & 3, qr = tid & 15;
    const int q0 = wave * 16;
    const int qe = (q0 + qr < 100) ? (q0 + qr) : 99;
    const float* qp = q4 + ((size_t)bh * 100 + qe) * 32 + g * 8;
    float4 qa = *(const float4*)qp;
    float4 qc = *(const float4*)(qp + 4);
    const unsigned char* mrow = maskp + ((size_t)b * 100 + qe) * MASKP;
    unsigned mpre[14];
    #pragma unroll
    for (int c = 0; c < 7; ++c) {
        mpre[2 * c]     = *(const unsigned*)(mrow + c * 32 + g * 4);
        mpre[2 * c + 1] = *(const unsigned*)(mrow + c * 32 + 16 + g * 4);
    }

    const float* kg_s  = kg  + (size_t)bh * VN_   * 32;
    const float* kn_s  = kn  + (size_t)bh * KNODE * 32;
    const float* kv_s  = kv  + (size_t)bh * KVEH  * 32;
    const float* kvn_s = kvn + (size_t)bh * KVND  * 32;
    const float* vg_s  = vg  + (size_t)bh * VN_   * 32;
    const float* vn_s  = vn  + (size_t)bh * KNODE * 32;
    const float* vv_s  = vv  + (size_t)bh * KVEH  * 32;
    const float* vvn_s = vvn + (size_t)bh * KVND  * 32;

    {
        float4 ka[4], kc[4];
        int koff[4]; bool kok[4];
        #pragma unroll
        for (int it = 0; it < 4; ++it) {
            int slot = tid + it * 512;
            kok[it] = slot < 1852;
            const float* sp; int li, r0;
            if (slot >= 1772)      { sp = kvn_s; li = slot - 1772; r0 = 456; }
            else if (slot >= 1688) { sp = kv_s;  li = slot - 1688; r0 = 432; }
            else if (slot >= 884)  { sp = kn_s;  li = slot - 884;  r0 = 224; }
            else                   { sp = kg_s;  li = slot;        r0 = 0;   }
            int r = li >> 2, s2 = li & 3;
            koff[it] = (r0 + r) * 80 + s2 * 16;
            if (kok[it]) {
                ka[it] = *(const float4*)(sp + r * 32 + s2 * 8);
                kc[it] = *(const float4*)(sp + r * 32 + s2 * 8 + 4);
            }
        }
        #pragma unroll
        for (int it = 0; it < 4; ++it) {
            if (kok[it]) {
                uint4 w;
                w.x = cvtpk(ka[it].x, ka[it].y); w.y = cvtpk(ka[it].z, ka[it].w);
                w.z = cvtpk(kc[it].x, kc[it].y); w.w = cvtpk(kc[it].z, kc[it].w);
                *(uint4*)(ldsb + K_OFF + koff[it]) = w;
            }
        }
    }
    for (int lin = tid; lin < 17 * 4; lin += 512) {
        int zi = lin >> 2, s = lin & 3;
        int zr = (zi < 3) ? 221 + zi : (zi < 10) ? 422 + zi
               : (zi < 13) ? 443 + zi : 463 + zi;
        *(uint4*)(ldsb + K_OFF + (size_t)zr * 80 + s * 16) = (uint4){0,0,0,0};
    }
    {
        char* vb = ldsb + V_OFF;
        float4 va[4], vb4[4];
        int vd0[4], vk2[4]; bool vok[4];
        #pragma unroll
        for (int it = 0; it < 4; ++it) {
            int slot = tid + it * 512;
            vok[it] = slot < 1840;
            const float* sp; int li, r0;
            if (slot >= 1760)      { sp = vvn_s; li = slot - 1760; r0 = 456; }
            else if (slot >= 1680) { sp = vv_s;  li = slot - 1680; r0 = 432; }
            else if (slot >= 880)  { sp = vn_s;  li = slot - 880;  r0 = 224; }
            else                   { sp = vg_s;  li = slot;        r0 = 0;   }
            int p = li >> 3, dq = li & 7;
            vd0[it] = dq * 4;
            vk2[it] = (r0 + 2 * p) * 2;
            if (vok[it]) {
                va[it]  = *(const float4*)(sp + (2 * p) * 32 + dq * 4);
                vb4[it] = *(const float4*)(sp + (2 * p + 1) * 32 + dq * 4);
            }
        }
        #pragma unroll
        for (int it = 0; it < 4; ++it) {
            if (vok[it]) {
                int d0 = vd0[it], k2 = vk2[it];
                *(unsigned*)(vb + (size_t)(d0 + 0) * 976 + k2) = cvtpk(va[it].x, vb4[it].x);
                *(unsigned*)(vb + (size_t)(d0 + 1) * 976 + k2) = cvtpk(va[it].y, vb4[it].y);
                *(unsigned*)(vb + (size_t)(d0 + 2) * 976 + k2) = cvtpk(va[it].z, vb4[it].z);
                *(unsigned*)(vb + (size_t)(d0 + 3) * 976 + k2) = cvtpk(va[it].w, vb4[it].w);
            }
        }
        if (tid < 32) {
            int d = tid;
            *(unsigned*)(vb + (size_t)d * 976 + 220 * 2) = cvtpk(vg_s[220 * 32 + d], 0.f);
            *(unsigned*)(vb + (size_t)d * 976 + 424 * 2) = cvtpk(vn_s[200 * 32 + d], 0.f);
            *(unsigned*)(vb + (size_t)d * 976 + 452 * 2) = cvtpk(vv_s[20 * 32 + d], 0.f);
        }
        for (int lin = tid; lin < 7 * 32; lin += 512) {
            int pi = lin >> 5, d = lin & 31;
            int pk = (pi == 0) ? 222 : (pi < 4) ? 424 + 2 * pi
                   : (pi == 4) ? 454 : 466 + 2 * pi;
            *(unsigned*)(vb + (size_t)d * 976 + (size_t)pk * 2) = 0;
        }
    }
    __syncthreads();

    if (wave >= 7) return;

    short8 qf;
    {
        const float SC = 0.2550524218f;    // 32^-.5 * log2(e)
        union { unsigned u[4]; short8 s8; } q;
        q.u[0] = cvtpk(qa.x * SC, qa.y * SC);
        q.u[1] = cvtpk(qa.z * SC, qa.w * SC);
        q.u[2] = cvtpk(qc.x * SC, qc.y * SC);
        q.u[3] = cvtpk(qc.z * SC, qc.w * SC);
        qf = q.s8;
    }
    const int addrA = 4 * (qr + ((g & 1) << 5));
    const int addrB = addrA + 64;

    f32x4 O0 = {0.f,0.f,0.f,0.f}, O1 = {0.f,0.f,0.f,0.f};
    attend_v5<true,  0,  6,   0, 224>(ldsb, mpre, qf, g, qr, addrA, addrB, O0, O1);
    attend_v5<false, 7, 13, 224, 425>(ldsb, nullptr, qf, g, qr, addrA, addrB, O0, O1);
    attend_v5<false,13, 14, 432, 453>(ldsb, nullptr, qf, g, qr, addrA, addrB, O0, O1);
    attend_v5<false,14, 14, 456, 476>(ldsb, nullptr, qf, g, qr, addrA, addrB, O0, O1);

    if (q0 + qr < 100) {
        float* op = ctx_out + ((size_t)b * 100 + q0 + qr) * 512 + nh * 32 + 4 * g;
        *(f32x4*)op        = O0;
        *(f32x4*)(op + 16) = O1;
    }
}

// ------------------------------------------------------------------
// n-fused GEMM: block = 64 m-rows x 256 n-cols; 512 thr, 8 waves (2m x 4n),
// wave 32x64 via 2x4 frags (acc 32 VGPR). A re-read 8x -> 2x.
// QPROJ=true: A = concat(qg[512], cf[16], 0-pad), W row-stride 528, K=544.
// QPROJ=false: A = ctx, W row-stride 512, K=512, + bias.
// ------------------------------------------------------------------
template<bool QPROJ>
__global__ __launch_bounds__(512, 4) void gemm_nfused(
    const float* __restrict__ Aq, const float* __restrict__ cf,
    const float* __restrict__ W,  const float* __restrict__ bias,
    float* __restrict__ outp)
{
    __shared__ char As[64 * 80];     // 5120 B
    __shared__ char Bs[256 * 80];    // 20480 B
    const int tid = threadIdx.x;
    const int n0 = blockIdx.x * 256, m0 = blockIdx.y * 64;
    const int wave = tid >> 6, lane = tid & 63;
    const int wm = wave >> 2, wn = wave & 3;
    const int g = lane >> 4, qr = lane & 15;
    // A staging slot: r=row(0..63), s=quad-of-4 (0..7)
    const int ar = tid >> 3, as = tid & 7;
    constexpr int KTOT_ = QPROJ ? 544 : 512;
    constexpr int WSTR  = QPROJ ? 528 : 512;

    f32x4 acc[2][4] = {};
    for (int k0 = 0; k0 < KTOT_; k0 += 32) {
        // ---- phase 1: issue all loads (overlap prior compute) ----
        float4 a4 = {0,0,0,0};
        {
            const int k = k0 + as * 4;
            if (!QPROJ || k < 512) {
                a4 = *(const float4*)(Aq + (size_t)(m0 + ar) * 512 + (QPROJ ? k : k));
            } else if (k < 528) {
                a4 = *(const float4*)(cf + (size_t)(m0 + ar) * 16 + (k - 512));
            }
        }
        float4 b0[2], b1[2];
        #pragma unroll
        for (int it = 0; it < 2; ++it) {
            int slot = tid + it * 512;          // 0..1023
            int row = slot >> 2, sq = slot & 3; // row 0..255, sq 0..3
            int k = k0 + sq * 8;
            b0[it] = (float4){0,0,0,0}; b1[it] = (float4){0,0,0,0};
            if (!QPROJ || k < 528) {
                const float* wp = W + (size_t)(n0 + row) * WSTR + k;
                b0[it] = *(const float4*)wp;
                b1[it] = *(const float4*)(wp + 4);
            }
        }
        __syncthreads();    // previous compute done before overwrite
        // ---- phase 2: convert + write ----
        {
            uint2 w;
            w.x = cvtpk(a4.x, a4.y); w.y = cvtpk(a4.z, a4.w);
            *(uint2*)(As + ar * 80 + as * 8) = w;
        }
        #pragma unroll
        for (int it = 0; it < 2; ++it) {
            int slot = tid + it * 512;
            int row = slot >> 2, sq = slot & 3;
            uint4 w;
            w.x = cvtpk(b0[it].x, b0[it].y); w.y = cvtpk(b0[it].z, b0[it].w);
            w.z = cvtpk(b1[it].x, b1[it].y); w.w = cvtpk(b1[it].z, b1[it].w);
            *(uint4*)(Bs + row * 80 + sq * 16) = w;
        }
        __syncthreads();
        // ---- compute: 2x4 frags ----
        short8 af0 = *(const short8*)(As + (wm * 32 + qr) * 80 + g * 16);
        short8 af1 = *(const short8*)(As + (wm * 32 + 16 + qr) * 80 + g * 16);
        #pragma unroll
        for (int nj = 0; nj < 4; ++nj) {
            short8 bf = *(const short8*)(Bs + (wn * 64 + nj * 16 + qr) * 80 + g * 16);
            acc[0][nj] = __builtin_amdgcn_mfma_f32_16x16x32_bf16(af0, bf, acc[0][nj], 0, 0, 0);
            acc[1][nj] = __builtin_amdgcn_mfma_f32_16x16x32_bf16(af1, bf, acc[1][nj], 0, 0, 0);
        }
    }
    // ---- epilogue ----
    #pragma unroll
    for (int mi = 0; mi < 2; ++mi)
        #pragma unroll
        for (int nj = 0; nj < 4; ++nj) {
            const int n = n0 + wn * 64 + nj * 16 + qr;
            const float bia = QPROJ ? 0.f : bias[n];
            #pragma unroll
            for (int reg = 0; reg < 4; ++reg) {
                int m = m0 + wm * 32 + 16 * mi + 4 * g + reg;
                if (QPROJ) {
                    int bb = m / 100, p = m - bb * 100;
                    int nh = n >> 5, d = n & 31;
                    outp[(((size_t)bb * NH_ + nh) * P_ + p) * HD_ + d] = acc[mi][nj][reg];
                } else {
                    outp[(size_t)m * 512 + n] = acc[mi][nj][reg] + bia;
                }
            }
        }
}

// ------------------------------------------------------------------
// logits MFMA: per b, out[p,key] = sum_h mha[b,p,h]*cp[b,h,key]
// ------------------------------------------------------------------
__global__ __launch_bounds__(512) void logits_mfma(
    const float* __restrict__ mha,   // [B*P, 512]
    const float* __restrict__ cp,    // [B, 512, VN]
    float* __restrict__ out)         // [B*P, VN]
{
    __shared__ char As[128 * 80];
    __shared__ char Bs[224 * 80];
    const int b = blockIdx.x;
    const int tid = threadIdx.x;
    const int wave = tid >> 6, lane = tid & 63;
    const int g = lane >> 4, qr = lane & 15;
    const int row = tid >> 2, s = tid & 3;

    f32x4 acc[14] = {};
    for (int h0 = 0; h0 < 512; h0 += 32) {
        uint4 wa = {0,0,0,0};
        if (row < 100) {
            const float* mp = mha + ((size_t)b * P_ + row) * 512 + h0 + 8 * s;
            float4 a = *(const float4*)mp;
            float4 c = *(const float4*)(mp + 4);
            wa.x = f2bf(a.x) | (f2bf(a.y) << 16);
            wa.y = f2bf(a.z) | (f2bf(a.w) << 16);
            wa.z = f2bf(c.x) | (f2bf(c.y) << 16);
            wa.w = f2bf(c.z) | (f2bf(c.w) << 16);
        }
        __syncthreads();
        *(uint4*)(As + row * 80 + s * 16) = wa;
        for (int lin = tid; lin < 224 * 8; lin += 512) {
            int kk = lin % 224, hq = lin / 224;
            int h = hq * 4;
            float v0 = 0.f, v1 = 0.f, v2 = 0.f, v3 = 0.f;
            if (kk < VN_) {
                const float* cpp = cp + ((size_t)b * 512 + h0 + h) * VN_ + kk;
                v0 = cpp[0]; v1 = cpp[VN_]; v2 = cpp[2 * VN_]; v3 = cpp[3 * VN_];
            }
            uint2 w;
            w.x = f2bf(v0) | (f2bf(v1) << 16);
            w.y = f2bf(v2) | (f2bf(v3) << 16);
            *(uint2*)(Bs + kk * 80 + h * 2) = w;
        }
        __syncthreads();
        short8 af = *(const short8*)(As + (wave * 16 + qr) * 80 + g * 16);
        #pragma unroll
        for (int ni = 0; ni < 14; ++ni) {
            short8 bf = *(const short8*)(Bs + (ni * 16 + qr) * 80 + g * 16);
            acc[ni] = __builtin_amdgcn_mfma_f32_16x16x32_bf16(af, bf, acc[ni], 0, 0, 0);
        }
    }
    #pragma unroll
    for (int ni = 0; ni < 14; ++ni) {
        int key = ni * 16 + qr;
        if (key >= VN_) continue;
        #pragma unroll
        for (int reg = 0; reg < 4; ++reg) {
            int p = wave * 16 + 4 * g + reg;
            if (p < P_)
                out[((size_t)b * P_ + p) * VN_ + key] = acc[ni][reg];
        }
    }
}

// ------------------------------------------------------------------
extern "C" void kernel_launch(void* const* d_in, const int* in_sizes, int n_in,
                              void* d_out, int out_size, void* d_ws, size_t ws_size,
                              hipStream_t stream) {
    const float* qg   = (const float*)d_in[0];
    const float* kgl  = (const float*)d_in[1];
    const float* vgl  = (const float*)d_in[2];
    const float* knd  = (const float*)d_in[3];
    const float* vnd  = (const float*)d_in[4];
    const float* kvh  = (const float*)d_in[5];
    const float* vvh  = (const float*)d_in[6];
    const float* kvnd = (const float*)d_in[7];
    const float* vvnd = (const float*)d_in[8];
    const float* cf   = (const float*)d_in[9];
    const float* cp   = (const float*)d_in[10];
    const void*  mask_raw = d_in[11];
    const float* Wq   = (const float*)d_in[12];
    const float* Wc   = (const float*)d_in[13];
    const float* bias = (const float*)d_in[14];
    float* out = (float*)d_out;

    const size_t NQ = (size_t)B_ * NH_ * P_ * HD_;   // 13,107,200 f32
    float* q4buf  = (float*)d_ws;
    float* ctxbuf = q4buf + NQ;
    float* mhabuf = q4buf;                            // reuse: q dead after attn
    unsigned char* mask8 = (unsigned char*)(ctxbuf + NQ);
    const int MASKN_P = B_ * P_ * MASKP;
    int* flag = (int*)(mask8 + ((MASKN_P + 15) & ~15));

    hipFuncSetAttribute(reinterpret_cast<const void*>(attn_mfma_kernel),
                        hipFuncAttributeMaxDynamicSharedMemorySize,
                        ATTN_LDS_B);

    hipMemsetAsync(flag, 0, sizeof(int), stream);
    mask_detect_kernel<<<16, 256, 0, stream>>>(
        (const unsigned int*)mask_raw, 4096, flag);
    mask_repack_kernel<<<(MASKN_P + 255) / 256, 256, 0, stream>>>(
        (const unsigned char*)mask_raw, (const int*)mask_raw, flag, mask8);

    gemm_nfused<true><<<dim3(2, 400), 512, 0, stream>>>(qg, cf, Wq, nullptr, q4buf);
    attn_mfma_kernel<<<B_ * NH_, 512, ATTN_LDS_B, stream>>>(
        q4buf, kgl, vgl, knd, vnd, kvh, vvh, kvnd, vvnd, mask8, ctxbuf);
    gemm_nfused<false><<<dim3(2, 400), 512, 0, stream>>>(ctxbuf, nullptr, Wc, bias, mhabuf);
    logits_mfma<<<B_, 512, 0, stream>>>(mhabuf, cp, out);
}

// Round 14
// 337.357 us; speedup vs baseline: 1.7047x; 1.0720x over previous
//
#include <hip/hip_runtime.h>
#include <hip/hip_bf16.h>

#define B_   256
#define P_   100
#define H_   512
#define NH_  16
#define HD_  32
#define VN_  221
#define KNODE 201
#define KVEH  21
#define KVND  20
#define CSD_ 16
#define MASKP 224                       // padded mask row stride (aligned dwords)

typedef __attribute__((ext_vector_type(8))) short short8;
typedef __attribute__((ext_vector_type(4))) float f32x4;

// ---- attention LDS layout (bytes) ----
#define K_OFF   0
#define V_OFF   38400
#define ATTN_LDS_B 69632

__device__ __forceinline__ unsigned cvtpk(float lo, float hi) {
    unsigned r;
    asm("v_cvt_pk_bf16_f32 %0, %1, %2" : "=v"(r) : "v"(lo), "v"(hi));
    return r;
}
__device__ __forceinline__ unsigned f2bf(float f) {
    union { float f; unsigned u; } x; x.f = f;
    return (x.u + 0x7FFFu + ((x.u >> 16) & 1u)) >> 16;   // RNE bf16 bits
}

// ------------------------------------------------------------------
// mask dtype probe + repack to padded [B*P][224] u8 (pad = 1 = illegal)
// ------------------------------------------------------------------
__global__ void mask_detect_kernel(const unsigned int* __restrict__ w,
                                   int nwords, int* __restrict__ flag) {
    int i = blockIdx.x * 256 + threadIdx.x;
    if (i < nwords && (w[i] & ~1u)) atomicOr(flag, 1);
}

__global__ void mask_repack_kernel(const unsigned char* __restrict__ mb,
                                   const int* __restrict__ mw,
                                   const int* __restrict__ flag,
                                   unsigned char* __restrict__ out) {
    int i = blockIdx.x * blockDim.x + threadIdx.x;
    if (i >= B_ * P_ * MASKP) return;
    int row = i / MASKP, k = i - row * MASKP;
    unsigned char v = 1;
    if (k < VN_) {
        int src = row * VN_ + k;
        v = (*flag) ? (unsigned char)(mb[src] != 0) : (unsigned char)(mw[src] != 0);
    }
    out[i] = v;
}

// ------------------------------------------------------------------
// attention (r12 — unchanged)
// ------------------------------------------------------------------
template<bool MASKED, int C0, int C1, int LO, int HI>
__device__ __forceinline__ void attend_v5(
    const char* __restrict__ ldsb,
    const unsigned* __restrict__ mpre,
    short8 qf, int g, int qr, int addrA, int addrB,
    f32x4& O0, f32x4& O1)
{
    f32x4 A0a = {0.f,0.f,0.f,0.f}, A1a = {0.f,0.f,0.f,0.f};
    f32x4 A0b = {0.f,0.f,0.f,0.f}, A1b = {0.f,0.f,0.f,0.f};
    float ssum = 0.f;
    const bool sel = g < 2;
    #pragma unroll
    for (int c = C0; c <= C1; ++c) {
        const int kb = c * 32;
        short8 kf0 = *(const short8*)(ldsb + K_OFF + (size_t)(kb + qr) * 80 + g * 16);
        short8 kf1 = *(const short8*)(ldsb + K_OFF + (size_t)(kb + 16 + qr) * 80 + g * 16);
        __builtin_amdgcn_s_setprio(1);
        f32x4 s0 = __builtin_amdgcn_mfma_f32_16x16x32_bf16(
                       kf0, qf, (f32x4){0.f,0.f,0.f,0.f}, 0, 0, 0);
        f32x4 s1 = __builtin_amdgcn_mfma_f32_16x16x32_bf16(
                       kf1, qf, (f32x4){0.f,0.f,0.f,0.f}, 0, 0, 0);
        __builtin_amdgcn_s_setprio(0);
        unsigned mdw0 = 0, mdw1 = 0;
        if (MASKED) {
            mdw0 = mpre[2 * (c - C0)];
            mdw1 = mpre[2 * (c - C0) + 1];
        }
        float e0[4], e1[4];
        #pragma unroll
        for (int r = 0; r < 4; ++r) {
            const int key0 = kb + 4 * g + r;
            const int key1 = key0 + 16;
            float x0 = exp2f(s0[r]);             // log2e folded into qf scale
            float x1 = exp2f(s1[r]);
            bool ok0, ok1;
            if (MASKED) {
                ok0 = ((mdw0 >> (8 * r)) & 255u) == 0u;
                ok1 = ((mdw1 >> (8 * r)) & 255u) == 0u;
            } else {
                ok0 = (key0 >= LO) & (key0 < HI);
                ok1 = (key1 >= LO) & (key1 < HI);
            }
            e0[r] = ok0 ? x0 : 0.f;
            e1[r] = ok1 ? x1 : 0.f;
            ssum += e0[r] + e1[r];
        }
        unsigned w0 = cvtpk(e0[0], e0[1]), w1 = cvtpk(e0[2], e0[3]);
        unsigned w2 = cvtpk(e1[0], e1[1]), w3 = cvtpk(e1[2], e1[3]);
        int pA0 = __builtin_amdgcn_ds_bpermute(addrA, (int)w0);
        int pA1 = __builtin_amdgcn_ds_bpermute(addrA, (int)w1);
        int pB0 = __builtin_amdgcn_ds_bpermute(addrB, (int)w0);
        int pB1 = __builtin_amdgcn_ds_bpermute(addrB, (int)w1);
        int qA0 = __builtin_amdgcn_ds_bpermute(addrA, (int)w2);
        int qA1 = __builtin_amdgcn_ds_bpermute(addrA, (int)w3);
        int qB0 = __builtin_amdgcn_ds_bpermute(addrB, (int)w2);
        int qB1 = __builtin_amdgcn_ds_bpermute(addrB, (int)w3);
        union { int u[4]; short8 s8; } pf;
        pf.u[0] = sel ? pA0 : qA0;
        pf.u[1] = sel ? pA1 : qA1;
        pf.u[2] = sel ? pB0 : qB0;
        pf.u[3] = sel ? pB1 : qB1;
        short8 v0 = *(const short8*)(ldsb + V_OFF + (size_t)qr * 976 + kb * 2 + g * 16);
        short8 v1 = *(const short8*)(ldsb + V_OFF + (size_t)(qr + 16) * 976 + kb * 2 + g * 16);
        __builtin_amdgcn_s_setprio(1);
        if (c & 1) {
            A0b = __builtin_amdgcn_mfma_f32_16x16x32_bf16(v0, pf.s8, A0b, 0, 0, 0);
            A1b = __builtin_amdgcn_mfma_f32_16x16x32_bf16(v1, pf.s8, A1b, 0, 0, 0);
        } else {
            A0a = __builtin_amdgcn_mfma_f32_16x16x32_bf16(v0, pf.s8, A0a, 0, 0, 0);
            A1a = __builtin_amdgcn_mfma_f32_16x16x32_bf16(v1, pf.s8, A1a, 0, 0, 0);
        }
        __builtin_amdgcn_s_setprio(0);
    }
    ssum += __shfl_xor(ssum, 16);
    ssum += __shfl_xor(ssum, 32);
    const float inv = 1.f / ssum;
    O0 += (A0a + A0b) * inv;
    O1 += (A1a + A1b) * inv;
}

__global__ __launch_bounds__(512, 4) void attn_mfma_kernel(
    const float* __restrict__ q4,
    const float* __restrict__ kg,  const float* __restrict__ vg,
    const float* __restrict__ kn,  const float* __restrict__ vn,
    const float* __restrict__ kv,  const float* __restrict__ vv,
    const float* __restrict__ kvn, const float* __restrict__ vvn,
    const unsigned char* __restrict__ maskp,
    float* __restrict__ ctx_out)
{
    extern __shared__ char ldsb[];
    const int tid = threadIdx.x;
    const int bh = blockIdx.x, b = bh >> 4, nh = bh & 15;

    const int wave = tid >> 6;
    const int g = (tid >> 4) & 3, qr = tid & 15;
    const int q0 = wave * 16;
    const int qe = (q0 + qr < 100) ? (q0 + qr) : 99;
    const float* qp = q4 + ((size_t)bh * 100 + qe) * 32 + g * 8;
    float4 qa = *(const float4*)qp;
    float4 qc = *(const float4*)(qp + 4);
    const unsigned char* mrow = maskp + ((size_t)b * 100 + qe) * MASKP;
    unsigned mpre[14];
    #pragma unroll
    for (int c = 0; c < 7; ++c) {
        mpre[2 * c]     = *(const unsigned*)(mrow + c * 32 + g * 4);
        mpre[2 * c + 1] = *(const unsigned*)(mrow + c * 32 + 16 + g * 4);
    }

    const float* kg_s  = kg  + (size_t)bh * VN_   * 32;
    const float* kn_s  = kn  + (size_t)bh * KNODE * 32;
    const float* kv_s  = kv  + (size_t)bh * KVEH  * 32;
    const float* kvn_s = kvn + (size_t)bh * KVND  * 32;
    const float* vg_s  = vg  + (size_t)bh * VN_   * 32;
    const float* vn_s  = vn  + (size_t)bh * KNODE * 32;
    const float* vv_s  = vv  + (size_t)bh * KVEH  * 32;
    const float* vvn_s = vvn + (size_t)bh * KVND  * 32;

    {
        float4 ka[4], kc[4];
        int koff[4]; bool kok[4];
        #pragma unroll
        for (int it = 0; it < 4; ++it) {
            int slot = tid + it * 512;
            kok[it] = slot < 1852;
            const float* sp; int li, r0;
            if (slot >= 1772)      { sp = kvn_s; li = slot - 1772; r0 = 456; }
            else if (slot >= 1688) { sp = kv_s;  li = slot - 1688; r0 = 432; }
            else if (slot >= 884)  { sp = kn_s;  li = slot - 884;  r0 = 224; }
            else                   { sp = kg_s;  li = slot;        r0 = 0;   }
            int r = li >> 2, s2 = li & 3;
            koff[it] = (r0 + r) * 80 + s2 * 16;
            if (kok[it]) {
                ka[it] = *(const float4*)(sp + r * 32 + s2 * 8);
                kc[it] = *(const float4*)(sp + r * 32 + s2 * 8 + 4);
            }
        }
        #pragma unroll
        for (int it = 0; it < 4; ++it) {
            if (kok[it]) {
                uint4 w;
                w.x = cvtpk(ka[it].x, ka[it].y); w.y = cvtpk(ka[it].z, ka[it].w);
                w.z = cvtpk(kc[it].x, kc[it].y); w.w = cvtpk(kc[it].z, kc[it].w);
                *(uint4*)(ldsb + K_OFF + koff[it]) = w;
            }
        }
    }
    for (int lin = tid; lin < 17 * 4; lin += 512) {
        int zi = lin >> 2, s = lin & 3;
        int zr = (zi < 3) ? 221 + zi : (zi < 10) ? 422 + zi
               : (zi < 13) ? 443 + zi : 463 + zi;
        *(uint4*)(ldsb + K_OFF + (size_t)zr * 80 + s * 16) = (uint4){0,0,0,0};
    }
    {
        char* vb = ldsb + V_OFF;
        float4 va[4], vb4[4];
        int vd0[4], vk2[4]; bool vok[4];
        #pragma unroll
        for (int it = 0; it < 4; ++it) {
            int slot = tid + it * 512;
            vok[it] = slot < 1840;
            const float* sp; int li, r0;
            if (slot >= 1760)      { sp = vvn_s; li = slot - 1760; r0 = 456; }
            else if (slot >= 1680) { sp = vv_s;  li = slot - 1680; r0 = 432; }
            else if (slot >= 880)  { sp = vn_s;  li = slot - 880;  r0 = 224; }
            else                   { sp = vg_s;  li = slot;        r0 = 0;   }
            int p = li >> 3, dq = li & 7;
            vd0[it] = dq * 4;
            vk2[it] = (r0 + 2 * p) * 2;
            if (vok[it]) {
                va[it]  = *(const float4*)(sp + (2 * p) * 32 + dq * 4);
                vb4[it] = *(const float4*)(sp + (2 * p + 1) * 32 + dq * 4);
            }
        }
        #pragma unroll
        for (int it = 0; it < 4; ++it) {
            if (vok[it]) {
                int d0 = vd0[it], k2 = vk2[it];
                *(unsigned*)(vb + (size_t)(d0 + 0) * 976 + k2) = cvtpk(va[it].x, vb4[it].x);
                *(unsigned*)(vb + (size_t)(d0 + 1) * 976 + k2) = cvtpk(va[it].y, vb4[it].y);
                *(unsigned*)(vb + (size_t)(d0 + 2) * 976 + k2) = cvtpk(va[it].z, vb4[it].z);
                *(unsigned*)(vb + (size_t)(d0 + 3) * 976 + k2) = cvtpk(va[it].w, vb4[it].w);
            }
        }
        if (tid < 32) {
            int d = tid;
            *(unsigned*)(vb + (size_t)d * 976 + 220 * 2) = cvtpk(vg_s[220 * 32 + d], 0.f);
            *(unsigned*)(vb + (size_t)d * 976 + 424 * 2) = cvtpk(vn_s[200 * 32 + d], 0.f);
            *(unsigned*)(vb + (size_t)d * 976 + 452 * 2) = cvtpk(vv_s[20 * 32 + d], 0.f);
        }
        for (int lin = tid; lin < 7 * 32; lin += 512) {
            int pi = lin >> 5, d = lin & 31;
            int pk = (pi == 0) ? 222 : (pi < 4) ? 424 + 2 * pi
                   : (pi == 4) ? 454 : 466 + 2 * pi;
            *(unsigned*)(vb + (size_t)d * 976 + (size_t)pk * 2) = 0;
        }
    }
    __syncthreads();

    if (wave >= 7) return;

    short8 qf;
    {
        const float SC = 0.2550524218f;    // 32^-.5 * log2(e)
        union { unsigned u[4]; short8 s8; } q;
        q.u[0] = cvtpk(qa.x * SC, qa.y * SC);
        q.u[1] = cvtpk(qa.z * SC, qa.w * SC);
        q.u[2] = cvtpk(qc.x * SC, qc.y * SC);
        q.u[3] = cvtpk(qc.z * SC, qc.w * SC);
        qf = q.s8;
    }
    const int addrA = 4 * (qr + ((g & 1) << 5));
    const int addrB = addrA + 64;

    f32x4 O0 = {0.f,0.f,0.f,0.f}, O1 = {0.f,0.f,0.f,0.f};
    attend_v5<true,  0,  6,   0, 224>(ldsb, mpre, qf, g, qr, addrA, addrB, O0, O1);
    attend_v5<false, 7, 13, 224, 425>(ldsb, nullptr, qf, g, qr, addrA, addrB, O0, O1);
    attend_v5<false,13, 14, 432, 453>(ldsb, nullptr, qf, g, qr, addrA, addrB, O0, O1);
    attend_v5<false,14, 14, 456, 476>(ldsb, nullptr, qf, g, qr, addrA, addrB, O0, O1);

    if (q0 + qr < 100) {
        float* op = ctx_out + ((size_t)b * 100 + q0 + qr) * 512 + nh * 32 + 4 * g;
        *(f32x4*)op        = O0;
        *(f32x4*)(op + 16) = O1;
    }
}

// ------------------------------------------------------------------
// n-fused GEMM (r13 — unchanged)
// ------------------------------------------------------------------
template<bool QPROJ>
__global__ __launch_bounds__(512, 4) void gemm_nfused(
    const float* __restrict__ Aq, const float* __restrict__ cf,
    const float* __restrict__ W,  const float* __restrict__ bias,
    float* __restrict__ outp)
{
    __shared__ char As[64 * 80];
    __shared__ char Bs[256 * 80];
    const int tid = threadIdx.x;
    const int n0 = blockIdx.x * 256, m0 = blockIdx.y * 64;
    const int wave = tid >> 6, lane = tid & 63;
    const int wm = wave >> 2, wn = wave & 3;
    const int g = lane >> 4, qr = lane & 15;
    const int ar = tid >> 3, as = tid & 7;
    constexpr int KTOT_ = QPROJ ? 544 : 512;
    constexpr int WSTR  = QPROJ ? 528 : 512;

    f32x4 acc[2][4] = {};
    for (int k0 = 0; k0 < KTOT_; k0 += 32) {
        float4 a4 = {0,0,0,0};
        {
            const int k = k0 + as * 4;
            if (!QPROJ || k < 512) {
                a4 = *(const float4*)(Aq + (size_t)(m0 + ar) * 512 + k);
            } else if (k < 528) {
                a4 = *(const float4*)(cf + (size_t)(m0 + ar) * 16 + (k - 512));
            }
        }
        float4 b0[2], b1[2];
        #pragma unroll
        for (int it = 0; it < 2; ++it) {
            int slot = tid + it * 512;
            int row = slot >> 2, sq = slot & 3;
            int k = k0 + sq * 8;
            b0[it] = (float4){0,0,0,0}; b1[it] = (float4){0,0,0,0};
            if (!QPROJ || k < 528) {
                const float* wp = W + (size_t)(n0 + row) * WSTR + k;
                b0[it] = *(const float4*)wp;
                b1[it] = *(const float4*)(wp + 4);
            }
        }
        __syncthreads();
        {
            uint2 w;
            w.x = cvtpk(a4.x, a4.y); w.y = cvtpk(a4.z, a4.w);
            *(uint2*)(As + ar * 80 + as * 8) = w;
        }
        #pragma unroll
        for (int it = 0; it < 2; ++it) {
            int slot = tid + it * 512;
            int row = slot >> 2, sq = slot & 3;
            uint4 w;
            w.x = cvtpk(b0[it].x, b0[it].y); w.y = cvtpk(b0[it].z, b0[it].w);
            w.z = cvtpk(b1[it].x, b1[it].y); w.w = cvtpk(b1[it].z, b1[it].w);
            *(uint4*)(Bs + row * 80 + sq * 16) = w;
        }
        __syncthreads();
        short8 af0 = *(const short8*)(As + (wm * 32 + qr) * 80 + g * 16);
        short8 af1 = *(const short8*)(As + (wm * 32 + 16 + qr) * 80 + g * 16);
        #pragma unroll
        for (int nj = 0; nj < 4; ++nj) {
            short8 bf = *(const short8*)(Bs + (wn * 64 + nj * 16 + qr) * 80 + g * 16);
            acc[0][nj] = __builtin_amdgcn_mfma_f32_16x16x32_bf16(af0, bf, acc[0][nj], 0, 0, 0);
            acc[1][nj] = __builtin_amdgcn_mfma_f32_16x16x32_bf16(af1, bf, acc[1][nj], 0, 0, 0);
        }
    }
    #pragma unroll
    for (int mi = 0; mi < 2; ++mi)
        #pragma unroll
        for (int nj = 0; nj < 4; ++nj) {
            const int n = n0 + wn * 64 + nj * 16 + qr;
            const float bia = QPROJ ? 0.f : bias[n];
            #pragma unroll
            for (int reg = 0; reg < 4; ++reg) {
                int m = m0 + wm * 32 + 16 * mi + 4 * g + reg;
                if (QPROJ) {
                    int bb = m / 100, p = m - bb * 100;
                    int nh = n >> 5, d = n & 31;
                    outp[(((size_t)bb * NH_ + nh) * P_ + p) * HD_ + d] = acc[mi][nj][reg];
                } else {
                    outp[(size_t)m * 512 + n] = acc[mi][nj][reg] + bia;
                }
            }
        }
}

// ------------------------------------------------------------------
// logits MFMA v2: grid = (b, key-half). Block handles 112 keys, all 100 p.
// 2 blocks/CU (19 KB LDS), two-phase staging (loads overlap prior MFMAs).
// ------------------------------------------------------------------
__global__ __launch_bounds__(512, 4) void logits_mfma(
    const float* __restrict__ mha,   // [B*P, 512]
    const float* __restrict__ cp,    // [B, 512, VN]
    float* __restrict__ out)         // [B*P, VN]
{
    __shared__ char As[128 * 80];    // 10240
    __shared__ char Bs[112 * 80];    // 8960
    const int b   = blockIdx.x >> 1;
    const int nh0 = (blockIdx.x & 1) * 112;   // key-range start
    const int tid = threadIdx.x;
    const int wave = tid >> 6, lane = tid & 63;
    const int g = lane >> 4, qr = lane & 15;
    const int row = tid >> 2, s = tid & 3;

    f32x4 acc[7] = {};
    for (int h0 = 0; h0 < 512; h0 += 32) {
        // ---- phase 1: issue all loads (overlap prior compute) ----
        float4 a4 = {0,0,0,0}, c4 = {0,0,0,0};
        if (row < 100) {
            const float* mp = mha + ((size_t)b * P_ + row) * 512 + h0 + 8 * s;
            a4 = *(const float4*)mp;
            c4 = *(const float4*)(mp + 4);
        }
        // cp: 112 keys x 8 h-quads = 896 slots
        float cv[2][4];
        int ckk[2], chq[2]; bool cok[2];
        #pragma unroll
        for (int it = 0; it < 2; ++it) {
            int slot = tid + it * 512;
            bool in = slot < 896;
            int kkl = in ? (slot % 112) : 0;
            int hq  = in ? (slot / 112) : 0;
            int kk  = nh0 + kkl;
            ckk[it] = kkl; chq[it] = hq;
            cok[it] = in;
            cv[it][0] = cv[it][1] = cv[it][2] = cv[it][3] = 0.f;
            if (in && kk < VN_) {
                const float* cpp = cp + ((size_t)b * 512 + h0 + hq * 4) * VN_ + kk;
                cv[it][0] = cpp[0];
                cv[it][1] = cpp[VN_];
                cv[it][2] = cpp[2 * VN_];
                cv[it][3] = cpp[3 * VN_];
            }
        }
        __syncthreads();    // prior compute done before overwrite
        // ---- phase 2: convert + write ----
        {
            uint4 w;
            w.x = cvtpk(a4.x, a4.y); w.y = cvtpk(a4.z, a4.w);
            w.z = cvtpk(c4.x, c4.y); w.w = cvtpk(c4.z, c4.w);
            *(uint4*)(As + row * 80 + s * 16) = w;
        }
        #pragma unroll
        for (int it = 0; it < 2; ++it) {
            if (cok[it]) {
                uint2 w;
                w.x = cvtpk(cv[it][0], cv[it][1]);
                w.y = cvtpk(cv[it][2], cv[it][3]);
                *(uint2*)(Bs + ckk[it] * 80 + chq[it] * 8) = w;
            }
        }
        __syncthreads();
        // ---- compute: 7 n-frags ----
        short8 af = *(const short8*)(As + (wave * 16 + qr) * 80 + g * 16);
        #pragma unroll
        for (int ni = 0; ni < 7; ++ni) {
            short8 bf = *(const short8*)(Bs + (ni * 16 + qr) * 80 + g * 16);
            acc[ni] = __builtin_amdgcn_mfma_f32_16x16x32_bf16(af, bf, acc[ni], 0, 0, 0);
        }
    }
    #pragma unroll
    for (int ni = 0; ni < 7; ++ni) {
        int key = nh0 + ni * 16 + qr;
        if (key >= VN_) continue;
        #pragma unroll
        for (int reg = 0; reg < 4; ++reg) {
            int p = wave * 16 + 4 * g + reg;
            if (p < P_)
                out[((size_t)b * P_ + p) * VN_ + key] = acc[ni][reg];
        }
    }
}

// ------------------------------------------------------------------
extern "C" void kernel_launch(void* const* d_in, const int* in_sizes, int n_in,
                              void* d_out, int out_size, void* d_ws, size_t ws_size,
                              hipStream_t stream) {
    const float* qg   = (const float*)d_in[0];
    const float* kgl  = (const float*)d_in[1];
    const float* vgl  = (const float*)d_in[2];
    const float* knd  = (const float*)d_in[3];
    const float* vnd  = (const float*)d_in[4];
    const float* kvh  = (const float*)d_in[5];
    const float* vvh  = (const float*)d_in[6];
    const float* kvnd = (const float*)d_in[7];
    const float* vvnd = (const float*)d_in[8];
    const float* cf   = (const float*)d_in[9];
    const float* cp   = (const float*)d_in[10];
    const void*  mask_raw = d_in[11];
    const float* Wq   = (const float*)d_in[12];
    const float* Wc   = (const float*)d_in[13];
    const float* bias = (const float*)d_in[14];
    float* out = (float*)d_out;

    const size_t NQ = (size_t)B_ * NH_ * P_ * HD_;   // 13,107,200 f32
    float* q4buf  = (float*)d_ws;
    float* ctxbuf = q4buf + NQ;
    float* mhabuf = q4buf;                            // reuse: q dead after attn
    unsigned char* mask8 = (unsigned char*)(ctxbuf + NQ);
    const int MASKN_P = B_ * P_ * MASKP;
    int* flag = (int*)(mask8 + ((MASKN_P + 15) & ~15));

    hipFuncSetAttribute(reinterpret_cast<const void*>(attn_mfma_kernel),
                        hipFuncAttributeMaxDynamicSharedMemorySize,
                        ATTN_LDS_B);

    hipMemsetAsync(flag, 0, sizeof(int), stream);
    mask_detect_kernel<<<16, 256, 0, stream>>>(
        (const unsigned int*)mask_raw, 4096, flag);
    mask_repack_kernel<<<(MASKN_P + 255) / 256, 256, 0, stream>>>(
        (const unsigned char*)mask_raw, (const int*)mask_raw, flag, mask8);

    gemm_nfused<true><<<dim3(2, 400), 512, 0, stream>>>(qg, cf, Wq, nullptr, q4buf);
    attn_mfma_kernel<<<B_ * NH_, 512, ATTN_LDS_B, stream>>>(
        q4buf, kgl, vgl, knd, vnd, kvh, vvh, kvnd, vvnd, mask8, ctxbuf);
    gemm_nfused<false><<<dim3(2, 400), 512, 0, stream>>>(ctxbuf, nullptr, Wc, bias, mhabuf);
    logits_mfma<<<B_ * 2, 512, 0, stream>>>(mhabuf, cp, out);
}